// Round 7
// baseline (582.606 us; speedup 1.0000x reference)
//
#include <hip/hip_runtime.h>
#include <hip/hip_bf16.h>

#define B_ 2
#define N_ 4096
#define M_ 12288
#define K_ 64
#define SH_ 32
#define H_ 64
#define GK_ 8
#define NC_ 200

#define SROWS 8        // rows (waves) per sampler block
#define TILE_ 2048     // float4 elements per tile half
#define CAP_ 96        // sampler boundary-candidate capacity

#define KCAP 352       // knn candidate capacity per row (lambda=200, +10 sigma)
#define KROWS 16       // knn rows per block (8 waves x 2 rows)

// monotone map float -> uint32 (ascending), and inverse
static __device__ __forceinline__ unsigned f2key(float f) {
  unsigned b = __float_as_uint(f);
  return (b & 0x80000000u) ? ~b : (b | 0x80000000u);
}
static __device__ __forceinline__ float key2f(unsigned u) {
  unsigned b = (u & 0x80000000u) ? (u & 0x7fffffffu) : ~u;
  return __uint_as_float(b);
}
static __device__ __forceinline__ unsigned long long shflxor64(unsigned long long x, int m) {
  unsigned lo = (unsigned)x, hi = (unsigned)(x >> 32);
  lo = (unsigned)__shfl_xor((int)lo, m);
  hi = (unsigned)__shfl_xor((int)hi, m);
  return ((unsigned long long)hi << 32) | lo;
}
// branchless sorted-descending insert into top[0..7] (u64 packed keys)
static __device__ __forceinline__ void ins8(unsigned long long* top, unsigned long long pk) {
  if (pk > top[7]) {
    bool c0=pk>top[0],c1=pk>top[1],c2=pk>top[2],c3=pk>top[3],c4=pk>top[4],c5=pk>top[5],c6=pk>top[6];
    top[7]=c6?top[6]:pk;
    top[6]=c5?top[5]:(c6?pk:top[6]);
    top[5]=c4?top[4]:(c5?pk:top[5]);
    top[4]=c3?top[3]:(c4?pk:top[4]);
    top[3]=c2?top[2]:(c3?pk:top[3]);
    top[2]=c1?top[1]:(c2?pk:top[2]);
    top[1]=c0?top[0]:(c1?pk:top[1]);
    top[0]=c0?pk:top[0];
  }
}
// pack (s, j) for knn: larger = better (bigger s, then smaller j)
static __device__ __forceinline__ unsigned long long kpack(float s, int j) {
  return ((unsigned long long)f2key(s) << 14) | (unsigned)(16383 - j);
}

// cos + linear bin (sampler)
static __device__ __forceinline__ int binOf(const float4 v, const float4 p, float& c) {
  c = fminf(1.f, fmaxf(-1.f, fmaf(v.z, p.z, fmaf(v.y, p.y, v.x * p.x))));
  return min((int)fmaf(c, 128.f, 128.f), 255);
}

// ---------------- sentinel ----------------
__global__ __launch_bounds__(256) void sentinel_v7(float* out, int n, float val) {
  int t = blockIdx.x * 256 + threadIdx.x;
  if (t < n) out[t] = val;
}

// ---------------- prep ----------------
__global__ __launch_bounds__(256) void prep_v7(
    const float* __restrict__ xxx, const float* __restrict__ pix,
    float4* __restrict__ r_pix, float4* __restrict__ r_los, float* __restrict__ gf)
{
  int tid = blockIdx.x * 256 + threadIdx.x;
  if (tid < M_) {
    float th = pix[2*tid], ph = pix[2*tid+1];
    float st = sinf(th);
    float x = st*cosf(ph), y = st*sinf(ph), z = cosf(th);
    r_pix[tid] = make_float4(x, y, z, x*x + y*y + z*z);
  }
  int t2 = tid - M_;
  if (t2 >= 0 && t2 < B_*N_) {
    int b = t2 >> 12, n = t2 & (N_-1);
    const float* xb = xxx + b*3*N_;
    float th = xb[n], ph = xb[N_+n], ft = xb[2*N_+n];
    float st = sinf(th);
    r_los[t2] = make_float4(st*cosf(ph), st*sinf(ph), cosf(th), ft);
  }
  int t3 = tid - M_ - B_*N_;
  if (t3 >= 0 && t3 < B_*H_) gf[t3] = 0.0f;
}

// ---------------- knn threshold: per-row alpha s.t. expected in-cap count = 200 ----------------
// density of points: theta ~ U[0,pi], phi ~ U[0,2pi]  =>  E(thp, a) = (M/2pi^2) * Int 2*acos(clamp(...)) dth
__global__ __launch_bounds__(256) void knnthr_v7(const float* __restrict__ pix, float* __restrict__ sthr)
{
  int i = blockIdx.x * 256 + threadIdx.x;
  if (i >= M_) return;
  const float PI = 3.14159265f;
  float thp = pix[2*i];
  float cp = cosf(thp);
  float spc = fmaxf(sinf(thp), 1e-6f);
  float lo = 1e-3f, hi = 3.141f;
  for (int it = 0; it < 20; ++it) {
    float al = 0.5f*(lo + hi);
    float ca = cosf(al);
    float t0 = fmaxf(0.f, thp - al), t1 = fminf(PI, thp + al);
    float dt = (t1 - t0) * (1.f/16.f);
    float A = 0.f;
    for (int q = 0; q < 16; ++q) {
      float th = t0 + ((float)q + 0.5f)*dt;
      float sn = fmaxf(sinf(th), 1e-6f);
      float arg = (ca - cosf(th)*cp) / (sn * spc);
      arg = fminf(1.f, fmaxf(-1.f, arg));
      A += acosf(arg);
    }
    A *= 2.f * dt;
    float E = (float)M_ * A / (2.f * PI * PI);
    if (E < 200.f) lo = al; else hi = al;
  }
  sthr[i] = 2.f*cosf(hi) - 1.00002f;   // hi end: E >= 200 guaranteed; slack for |r|^2 != 1
}

// ---------------- knn v7: threshold prefilter + exact top-8 from candidates ----------------
__global__ __launch_bounds__(512) void knn_v7(
    const float4* __restrict__ r_pix, const float* __restrict__ sthr, int* __restrict__ nbr)
{
  __shared__ float4 tile[2048];                      // 32 KB
  __shared__ unsigned long long cKey[KROWS][KCAP];   // 44 KB
  __shared__ unsigned cCnt[KROWS];

  const int tid  = threadIdx.x;
  const int wv   = tid >> 6;        // 0..7
  const int lane = tid & 63;
  const int lr0  = wv * 2;          // local rows for this wave
  const int i0   = blockIdx.x * KROWS + lr0;
  const int i1   = i0 + 1;

  if (tid < KROWS) cCnt[tid] = 0u;

  const float4 p0 = r_pix[i0];
  const float4 p1 = r_pix[i1];
  const float t0 = sthr[i0];
  const float t1 = sthr[i1];

  // ---- phase A: prefilter scan ----
  for (int jt = 0; jt < M_; jt += 2048) {
    __syncthreads();
    #pragma unroll
    for (int q = 0; q < 4; ++q) tile[tid + 512*q] = r_pix[jt + tid + 512*q];
    __syncthreads();
    for (int g = 0; g < 32; ++g) {
      int jj = lane + 64*g;
      float4 v = tile[jj];
      int j = jt + jj;
      float s0 = 2.f*(p0.x*v.x + p0.y*v.y + p0.z*v.z) - v.w;   // keep v6 arithmetic
      float s1 = 2.f*(p1.x*v.x + p1.y*v.y + p1.z*v.z) - v.w;
      if (j != i0 && s0 > t0) {
        unsigned sl = atomicAdd(&cCnt[lr0], 1u);
        if (sl < KCAP) cKey[lr0][sl] = kpack(s0, j);
      }
      if (j != i1 && s1 > t1) {
        unsigned sl = atomicAdd(&cCnt[lr0+1], 1u);
        if (sl < KCAP) cKey[lr0+1][sl] = kpack(s1, j);
      }
    }
  }
  __syncthreads();

  // ---- phase B: exact top-8 per row ----
  for (int rr = 0; rr < 2; ++rr) {
    const int lr = lr0 + rr;
    const int i  = i0 + rr;
    unsigned cnt = cCnt[lr];
    if (cnt >= 8u && cnt <= (unsigned)KCAP) {
      unsigned long long pk[6];
      #pragma unroll
      for (int t = 0; t < 6; ++t) {
        int idx = lane + 64*t;
        pk[t] = (idx < (int)cnt) ? cKey[lr][idx] : 0ull;
      }
      for (int round = 0; round < GK_; ++round) {
        unsigned long long loc = pk[0]; int lt = 0;
        #pragma unroll
        for (int t = 1; t < 6; ++t) if (pk[t] > loc) { loc = pk[t]; lt = t; }
        unsigned long long best = loc;
        #pragma unroll
        for (int off = 1; off < 64; off <<= 1) {
          unsigned long long o = shflxor64(best, off);
          best = o > best ? o : best;
        }
        if (loc == best) {    // unique owner (keys distinct)
          #pragma unroll
          for (int t = 0; t < 6; ++t) if (t == lt) pk[t] = 0ull;
        }
        if (lane == round) nbr[i*GK_ + round] = 16383 - (int)(best & 16383ull);
      }
    } else {
      // fallback: exact full scan (never expected)
      const float4 pi = (rr == 0) ? p0 : p1;
      unsigned long long top[8];
      #pragma unroll
      for (int k = 0; k < 8; ++k) top[k] = 0ull;
      for (int j = lane; j < M_; j += 64) {
        float4 v = r_pix[j];
        float s = 2.f*(pi.x*v.x + pi.y*v.y + pi.z*v.z) - v.w;
        if (j != i) ins8(top, kpack(s, j));
      }
      for (int round = 0; round < GK_; ++round) {
        unsigned long long best = top[0];
        #pragma unroll
        for (int off = 1; off < 64; off <<= 1) {
          unsigned long long o = shflxor64(best, off);
          best = o > best ? o : best;
        }
        if (top[0] == best) {
          #pragma unroll
          for (int k = 0; k < 7; ++k) top[k] = top[k+1];
          top[7] = 0ull;
        }
        if (lane == round) nbr[i*GK_ + round] = 16383 - (int)(best & 16383ull);
      }
    }
  }
}

// ---------------- sampler v6 (unchanged, proven) ----------------
__global__ __launch_bounds__(512) void sampler_v7(
    const float4* __restrict__ r_pix, const float4* __restrict__ r_los,
    const float* __restrict__ att_w1, const float* __restrict__ att_b1,
    const float* __restrict__ att_w2, const float* __restrict__ att_b2,
    float* __restrict__ pooled)
{
  __shared__ float4 tile[TILE_];
  __shared__ unsigned hist[SROWS][256];
  __shared__ float selC[SROWS][K_];
  __shared__ float selX[SROWS][K_];
  __shared__ unsigned long long bkey[SROWS][CAP_];
  __shared__ float bxg[SROWS][CAP_];
  __shared__ unsigned cHi[SROWS], cBd[SROWS], s_thr[SROWS];

  const int tid  = threadIdx.x;
  const int wv   = tid >> 6;
  const int lane = tid & 63;
  const int b    = blockIdx.y;
  const int m    = blockIdx.x * SROWS + wv;

  const float4 p = r_pix[m];
  const float4* rl = r_los + b * N_;

  #pragma unroll
  for (int q = 0; q < 4; ++q) ((unsigned*)hist)[tid + 512*q] = 0u;
  if (tid < SROWS) { cHi[tid] = 0u; cBd[tid] = 0u; }
  selC[wv][lane] = -1.0f;
  selX[wv][lane] = 0.0f;

  for (int hh = 0; hh < 2; ++hh) {
    __syncthreads();
    #pragma unroll
    for (int q = 0; q < TILE_/512; ++q)
      tile[tid + 512*q] = rl[hh*TILE_ + tid + 512*q];
    __syncthreads();
    for (int i = 0; i < TILE_/64; ++i) {
      float c;
      int bin = binOf(tile[lane + 64*i], p, c);
      atomicAdd(&hist[wv][bin], 1u);
    }
  }
  __syncthreads();

  {
    const int l = lane;
    unsigned h0 = hist[wv][4*l+0], h1 = hist[wv][4*l+1],
             h2 = hist[wv][4*l+2], h3 = hist[wv][4*l+3];
    unsigned g = h0 + h1 + h2 + h3;
    unsigned s = g;
    #pragma unroll
    for (int off = 1; off < 64; off <<= 1) {
      unsigned t = (unsigned)__shfl_down((int)s, off);
      s += (l + off < 64) ? t : 0u;
    }
    unsigned snext = s - g;
    unsigned c3 = h3 + snext, c2 = h2 + c3, c1 = h1 + c2, c0 = h0 + c1;
    unsigned packed = 0u;
    if      (c3 >= K_) packed = ((unsigned)(4*l+4) << 16) | snext;
    else if (c2 >= K_) packed = ((unsigned)(4*l+3) << 16) | c3;
    else if (c1 >= K_) packed = ((unsigned)(4*l+2) << 16) | c2;
    else if (c0 >= K_) packed = ((unsigned)(4*l+1) << 16) | c1;
    #pragma unroll
    for (int off = 32; off; off >>= 1) {
      unsigned o = (unsigned)__shfl_xor((int)packed, off);
      packed = packed > o ? packed : o;
    }
    if (l == 0) s_thr[wv] = (packed >> 16) - 1u;
  }
  __syncthreads();

  const int thr = (int)s_thr[wv];
  for (int hh = 0; hh < 2; ++hh) {
    __syncthreads();
    #pragma unroll
    for (int q = 0; q < TILE_/512; ++q)
      tile[tid + 512*q] = rl[hh*TILE_ + tid + 512*q];
    __syncthreads();
    for (int i = 0; i < TILE_/64; ++i) {
      int n0 = lane + 64*i;
      float4 v = tile[n0];
      float c;
      int bin = binOf(v, p, c);
      if (bin > thr) {
        unsigned slot = atomicAdd(&cHi[wv], 1u);
        if (slot < K_) { selC[wv][slot] = c; selX[wv][slot] = v.w; }
      } else if (bin == thr) {
        unsigned q2 = atomicAdd(&cBd[wv], 1u);
        if (q2 < CAP_) {
          int n = hh*TILE_ + n0;
          bkey[wv][q2] = ((unsigned long long)f2key(c) << 12) | (unsigned)(4095 - n);
          bxg[wv][q2]  = v.w;
        }
      }
    }
  }
  __syncthreads();

  {
    int above = (int)cHi[wv]; if (above > K_) above = K_;
    int need  = K_ - above;
    int cntB  = (int)cBd[wv]; if (cntB > CAP_) cntB = CAP_;
    for (int it = lane; it < cntB; it += 64) {
      unsigned long long mypk = bkey[wv][it];
      int rank = 0;
      for (int j = 0; j < cntB; ++j) rank += (bkey[wv][j] > mypk) ? 1 : 0;
      if (rank < need && above + rank < K_) {
        selC[wv][above + rank] = key2f((unsigned)(mypk >> 12));
        selX[wv][above + rank] = bxg[wv][it];
      }
    }
  }
  __syncthreads();

  {
    float c  = selC[wv][lane];
    float xg = selX[wv][lane];
    float d  = acosf(fminf(1.f, fmaxf(-1.f, c)));
    float acc = att_b2[0];
    for (int s = 0; s < SH_; ++s) {
      float t = xg * att_w1[s] + d * att_w1[SH_ + s] + att_b1[s];
      acc += fmaxf(t, 0.f) * att_w2[s];
    }
    float mx = acc;
    #pragma unroll
    for (int off = 32; off; off >>= 1) mx = fmaxf(mx, __shfl_xor(mx, off));
    float e = expf(acc - mx);
    float se = e, sxe = e * xg;
    #pragma unroll
    for (int off = 32; off; off >>= 1) { se += __shfl_xor(se, off); sxe += __shfl_xor(sxe, off); }
    if (lane == 0) pooled[b*M_ + m] = sxe / se;
  }
}

// ---------------- proj ----------------
__global__ __launch_bounds__(256) void proj_v7(
    const float* __restrict__ pooled, const float* __restrict__ proj_w,
    const float* __restrict__ proj_b, float* __restrict__ h0)
{
  int t = blockIdx.x * 256 + threadIdx.x;
  int c = t & (H_-1);
  int bm = t >> 6;
  float p = pooled[bm];
  h0[t] = fmaxf(p * proj_w[c] + proj_b[c], 0.f);
}

// ---------------- GNN layer ----------------
__global__ __launch_bounds__(256) void gnn_v7(
    const float* __restrict__ hin, float* __restrict__ hout, const int* __restrict__ nbr,
    const float* __restrict__ relw, const float* __restrict__ relb,
    const float* __restrict__ rootw)
{
  __shared__ float wrel[H_*H_], wroot[H_*H_], rb[H_];
  const int tid = threadIdx.x;
  #pragma unroll
  for (int q = 0; q < 16; ++q) {
    int idx = tid + 256*q;
    wrel[idx]  = relw[idx];
    wroot[idx] = rootw[idx];
  }
  if (tid < H_) rb[tid] = relb[tid];
  __syncthreads();

  const int lane = tid & 63;
  const int wave = tid >> 6;
  const int b = blockIdx.y;
  const int m0 = blockIdx.x * 16 + wave * 4;
  const float* hb = hin + (size_t)b * M_ * H_;

  float h[4], agg[4], acc[4];
  #pragma unroll
  for (int t = 0; t < 4; ++t) {
    int m = m0 + t;
    h[t] = hb[m*H_ + lane];
    float a = 0.f;
    #pragma unroll
    for (int k = 0; k < GK_; ++k) {
      int nb = nbr[m*GK_ + k];
      nb = nb < 0 ? 0 : (nb >= M_ ? M_-1 : nb);
      a += hb[nb*H_ + lane];
    }
    agg[t] = a;
    acc[t] = rb[lane];
  }
  for (int c = 0; c < H_; ++c) {
    float wr = wrel[c*H_ + lane], wo = wroot[c*H_ + lane];
    #pragma unroll
    for (int t = 0; t < 4; ++t) {
      float a  = __shfl(agg[t], c);
      float hh = __shfl(h[t], c);
      acc[t] += a * wr + hh * wo;
    }
  }
  #pragma unroll
  for (int t = 0; t < 4; ++t)
    hout[((size_t)b*M_ + m0 + t)*H_ + lane] = fmaxf(acc[t], 0.f);
}

// ---------------- reduce ----------------
__global__ __launch_bounds__(256) void reduce_v7(const float* __restrict__ h, float* __restrict__ gf)
{
  const int b = blockIdx.y;
  const int slice = blockIdx.x;
  const int c = threadIdx.x & 63, g = threadIdx.x >> 6;
  const float* hb = h + (size_t)b * M_ * H_;
  const int rows = M_ / 32;
  const int m0 = slice * rows;
  float s = 0.f;
  for (int r = g; r < rows; r += 4) s += hb[(m0 + r)*H_ + c];
  __shared__ float part[256];
  part[threadIdx.x] = s;
  __syncthreads();
  if (g == 0) {
    s = part[c] + part[64 + c] + part[128 + c] + part[192 + c];
    atomicAdd(&gf[b*H_ + c], s);
  }
}

// ---------------- head ----------------
__global__ __launch_bounds__(256) void head_v7(
    const float* __restrict__ gf, const float* __restrict__ w1,
    const float* __restrict__ b1, const float* __restrict__ w2,
    const float* __restrict__ b2, float* __restrict__ out)
{
  __shared__ float gfm[B_][H_], hid[B_][H_];
  const int tid = threadIdx.x;
  if (tid < B_*H_) gfm[tid >> 6][tid & 63] = gf[tid] * (1.f / (float)M_);
  __syncthreads();
  if (tid < B_*H_) {
    int b = tid >> 6, j = tid & 63;
    float acc = b1[j];
    for (int c = 0; c < H_; ++c) acc += gfm[b][c] * w1[c*H_ + j];
    hid[b][j] = fmaxf(acc, 0.f);
  }
  __syncthreads();
  for (int t = tid; t < B_*NC_; t += 256) {
    int b = t / NC_, o = t - b*NC_;
    float acc = b2[o];
    for (int j = 0; j < H_; ++j) acc += hid[b][j] * w2[j*NC_ + o];
    out[t] = acc;
  }
}

extern "C" void kernel_launch(void* const* d_in, const int* in_sizes, int n_in,
                              void* d_out, int out_size, void* d_ws, size_t ws_size,
                              hipStream_t stream)
{
  float* out = (float*)d_out;

  const size_t need = (size_t)M_*16 + (size_t)B_*N_*16 + (size_t)B_*M_*4
                    + (size_t)M_*GK_*4 + 2*(size_t)B_*M_*H_*4 + (size_t)B_*H_*4;
  bool ok_ws = ws_size >= need;
  bool ok_in = (n_in == 15) && (out_size == B_*NC_)
            && in_sizes[0] == B_*3*N_ && in_sizes[1] == M_*2
            && in_sizes[2] == 2*SH_ && in_sizes[5] == 1
            && in_sizes[8] == 3*H_*H_ && in_sizes[13] == H_*NC_;
  if (!ok_ws || !ok_in) {
    sentinel_v7<<<(out_size + 255)/256, 256, 0, stream>>>(out, out_size, ok_in ? 42.f : 43.f);
    return;
  }

  const float* xxx    = (const float*)d_in[0];
  const float* pix    = (const float*)d_in[1];
  const float* att_w1 = (const float*)d_in[2];
  const float* att_b1 = (const float*)d_in[3];
  const float* att_w2 = (const float*)d_in[4];
  const float* att_b2 = (const float*)d_in[5];
  const float* proj_w = (const float*)d_in[6];
  const float* proj_b = (const float*)d_in[7];
  const float* rel_w  = (const float*)d_in[8];
  const float* rel_b  = (const float*)d_in[9];
  const float* root_w = (const float*)d_in[10];
  const float* out_w1 = (const float*)d_in[11];
  const float* out_b1 = (const float*)d_in[12];
  const float* out_w2 = (const float*)d_in[13];
  const float* out_b2 = (const float*)d_in[14];

  char* w = (char*)d_ws;
  float4* r_pix = (float4*)w;  w += (size_t)M_ * 16;
  float4* r_los = (float4*)w;  w += (size_t)B_ * N_ * 16;
  float*  pooled = (float*)w;  w += (size_t)B_ * M_ * 4;
  int*    nbr = (int*)w;       w += (size_t)M_ * GK_ * 4;
  float*  h0 = (float*)w;      w += (size_t)B_ * M_ * H_ * 4;
  float*  h1 = (float*)w;      w += (size_t)B_ * M_ * H_ * 4;
  float*  gf = (float*)w;      w += (size_t)B_ * H_ * 4;
  float*  sthr = h1;           // alias: h1 unused until gnn layer 1 (after knn)

  prep_v7<<<(M_ + B_*N_ + B_*H_ + 255)/256, 256, 0, stream>>>(xxx, pix, r_pix, r_los, gf);
  knnthr_v7<<<(M_ + 255)/256, 256, 0, stream>>>(pix, sthr);
  sampler_v7<<<dim3(M_/SROWS, B_), 512, 0, stream>>>(r_pix, r_los, att_w1, att_b1, att_w2, att_b2, pooled);
  knn_v7<<<M_/KROWS, 512, 0, stream>>>(r_pix, sthr, nbr);
  proj_v7<<<(B_*M_*H_)/256, 256, 0, stream>>>(pooled, proj_w, proj_b, h0);
  gnn_v7<<<dim3(M_/16, B_), 256, 0, stream>>>(h0, h1, nbr, rel_w + 0*H_*H_, rel_b + 0*H_, root_w + 0*H_*H_);
  gnn_v7<<<dim3(M_/16, B_), 256, 0, stream>>>(h1, h0, nbr, rel_w + 1*H_*H_, rel_b + 1*H_, root_w + 1*H_*H_);
  gnn_v7<<<dim3(M_/16, B_), 256, 0, stream>>>(h0, h1, nbr, rel_w + 2*H_*H_, rel_b + 2*H_, root_w + 2*H_*H_);
  reduce_v7<<<dim3(32, B_), 256, 0, stream>>>(h1, gf);
  head_v7<<<1, 256, 0, stream>>>(gf, out_w1, out_b1, out_w2, out_b2, out);
}

// Round 8
// 480.217 us; speedup vs baseline: 1.2132x; 1.2132x over previous
//
#include <hip/hip_runtime.h>
#include <hip/hip_bf16.h>

#define B_ 2
#define N_ 4096
#define M_ 12288
#define K_ 64
#define SH_ 32
#define H_ 64
#define GK_ 8
#define NC_ 200

#define SCAP 352       // sampler candidate cap (E=192, +11.8 sigma)
#define KCAP 240       // knn candidate cap (E=128, +9.9 sigma)
#define KROWS 16

// monotone map float -> uint32 (ascending), and inverse
static __device__ __forceinline__ unsigned f2key(float f) {
  unsigned b = __float_as_uint(f);
  return (b & 0x80000000u) ? ~b : (b | 0x80000000u);
}
static __device__ __forceinline__ float key2f(unsigned u) {
  unsigned b = (u & 0x80000000u) ? (u & 0x7fffffffu) : ~u;
  return __uint_as_float(b);
}
static __device__ __forceinline__ unsigned long long shflxor64(unsigned long long x, int m) {
  unsigned lo = (unsigned)x, hi = (unsigned)(x >> 32);
  lo = (unsigned)__shfl_xor((int)lo, m);
  hi = (unsigned)__shfl_xor((int)hi, m);
  return ((unsigned long long)hi << 32) | lo;
}
static __device__ __forceinline__ unsigned long long kpack(float s, int j) {
  return ((unsigned long long)f2key(s) << 14) | (unsigned)(16383 - j);
}
static __device__ __forceinline__ unsigned long long spack(float c, int n) {
  return ((unsigned long long)f2key(c) << 12) | (unsigned)(4095 - n);
}

// ---------------- sentinel ----------------
__global__ __launch_bounds__(256) void sentinel_v8(float* out, int n, float val) {
  int t = blockIdx.x * 256 + threadIdx.x;
  if (t < n) out[t] = val;
}

// ---------------- prep + per-row thresholds (one wave per threshold job) ----------------
#define THRB_ 6144     // 2*M jobs / 4 waves per 256-thr block
#define PREPN_ (M_ + B_*N_ + B_*H_)
#define PREPB_ ((PREPN_ + 255)/256)

__global__ __launch_bounds__(256) void prepthr_v8(
    const float* __restrict__ xxx, const float* __restrict__ pix,
    float4* __restrict__ r_pix, float4* __restrict__ r_los, float* __restrict__ gf,
    float* __restrict__ kthr, float* __restrict__ cthr)
{
  const float PI = 3.14159265358979f;
  if ((int)blockIdx.x < THRB_) {
    int gid  = blockIdx.x*4 + (threadIdx.x >> 6);
    int lane = threadIdx.x & 63;
    int tgt  = (gid >= M_) ? 1 : 0;
    int row  = gid - tgt*M_;
    float thp = pix[2*row];
    float cp = cosf(thp), sp = fmaxf(sinf(thp), 1e-6f);
    float thq = ((float)lane + 0.5f) * (PI/64.f);
    float sq = sinf(thq), cq = cosf(thq);
    float rinv = 1.0f / (sq * sp);
    float At = tgt ? (2.f*PI*PI*192.f/(float)N_) : (2.f*PI*PI*128.f/(float)M_);
    float lo = 1e-3f, hi = 3.1414f;
    for (int it = 0; it < 22; ++it) {
      float al = 0.5f*(lo + hi);
      float ca = cosf(al);
      float arg = fminf(1.f, fmaxf(-1.f, (ca - cq*cp) * rinv));
      float ax = fabsf(arg);
      float ac = sqrtf(fmaxf(0.f, 1.f - ax)) *
                 fmaf(ax, fmaf(ax, fmaf(ax, -0.0187293f, 0.0742610f), -0.2121144f), 1.5707288f);
      ac = (arg < 0.f) ? (PI - ac) : ac;
      float S = ac;
      #pragma unroll
      for (int off = 32; off; off >>= 1) S += __shfl_xor(S, off);
      float A = 2.f * S * (PI/64.f);
      if (A < At) lo = al; else hi = al;
    }
    if (lane == 0) {
      float chv = cosf(hi);
      if (tgt) cthr[row] = chv - 1e-5f;          // cos-space, sampler
      else     kthr[row] = 2.f*chv - 1.00002f;   // s-space, knn
    }
  } else {
    int tid = ((int)blockIdx.x - THRB_)*256 + threadIdx.x;
    if (tid < M_) {
      float th = pix[2*tid], ph = pix[2*tid+1];
      float st = sinf(th);
      float x = st*cosf(ph), y = st*sinf(ph), z = cosf(th);
      r_pix[tid] = make_float4(x, y, z, x*x + y*y + z*z);
    }
    int t2 = tid - M_;
    if (t2 >= 0 && t2 < B_*N_) {
      int b = t2 >> 12, n = t2 & (N_-1);
      const float* xb = xxx + b*3*N_;
      float th = xb[n], ph = xb[N_+n], ft = xb[2*N_+n];
      float st = sinf(th);
      r_los[t2] = make_float4(st*cosf(ph), st*sinf(ph), cosf(th), ft);
    }
    int t3 = tid - M_ - B_*N_;
    if (t3 >= 0 && t3 < B_*H_) gf[t3] = 0.0f;
  }
}

// ---------------- sampler v8: prefilter + 128-bin select; global reads, no tile ----------------
__global__ __launch_bounds__(512) void sampler_v8(
    const float4* __restrict__ r_pix, const float4* __restrict__ r_los,
    const float* __restrict__ cthr,
    const float* __restrict__ aw1, const float* __restrict__ ab1,
    const float* __restrict__ aw2, const float* __restrict__ ab2,
    float* __restrict__ pooled)
{
  __shared__ unsigned long long cKey[16][SCAP];   // 45 KB
  __shared__ unsigned long long selKey[16][K_];   // 8 KB
  __shared__ unsigned hist[16][128];              // 8 KB
  __shared__ int bnd[16][16];                     // 1 KB  (total 62.4 KB)

  const int tid = threadIdx.x, wv = tid >> 6, lane = tid & 63;
  const int b  = blockIdx.y;
  const int m0 = blockIdx.x*16 + wv*2, m1 = m0 + 1;
  const int r0 = wv*2, r1 = r0 + 1;
  const float4 p0 = r_pix[m0], p1 = r_pix[m1];
  float th0 = cthr[m0], th1 = cthr[m1];
  const float4* rl = r_los + b * N_;
  const unsigned long long ltm = (1ull << lane) - 1ull;

  // phase A: prefilter scan, ballot-compacted candidate lists (wave-private)
  unsigned cnt0 = 0, cnt1 = 0;
  for (int i = 0; i < 64; ++i) {
    int n = lane + 64*i;
    float4 v = rl[n];
    float c0 = fminf(1.f, fmaxf(-1.f, v.x*p0.x + v.y*p0.y + v.z*p0.z));
    float c1 = fminf(1.f, fmaxf(-1.f, v.x*p1.x + v.y*p1.y + v.z*p1.z));
    bool pr0 = c0 > th0, pr1 = c1 > th1;
    unsigned long long mk0 = __ballot(pr0);
    if (mk0) {
      unsigned off = (unsigned)__popcll(mk0 & ltm);
      if (pr0 && cnt0 + off < SCAP) cKey[r0][cnt0 + off] = spack(c0, n);
      cnt0 += (unsigned)__popcll(mk0);
    }
    unsigned long long mk1 = __ballot(pr1);
    if (mk1) {
      unsigned off = (unsigned)__popcll(mk1 & ltm);
      if (pr1 && cnt1 + off < SCAP) cKey[r1][cnt1 + off] = spack(c1, n);
      cnt1 += (unsigned)__popcll(mk1);
    }
  }

  for (int rr = 0; rr < 2; ++rr) {
    const int r = (rr == 0) ? r0 : r1;
    const int m = (rr == 0) ? m0 : m1;
    const float4 p = (rr == 0) ? p0 : p1;
    float th = (rr == 0) ? th0 : th1;
    unsigned cn = (rr == 0) ? cnt0 : cnt1;

    // widen-retries (multiplicative in (1-cos)); overflow goes straight to ultimate
    int tries = 0;
    while (cn < K_ && tries < 3) {
      th = 1.f - 1.6f*(1.f - th); ++tries;
      cn = 0;
      for (int i = 0; i < 64; ++i) {
        int n = lane + 64*i;
        float4 v = rl[n];
        float c = fminf(1.f, fmaxf(-1.f, v.x*p.x + v.y*p.y + v.z*p.z));
        bool pr = c > th;
        unsigned long long mk = __ballot(pr);
        if (mk) {
          unsigned off = (unsigned)__popcll(mk & ltm);
          if (pr && cn + off < SCAP) cKey[r][cn + off] = spack(c, n);
          cn += (unsigned)__popcll(mk);
        }
      }
    }

    if (cn < K_ || cn > SCAP) {
      // ultimate exact path: 64 rounds of bounded argmax over the full row
      unsigned long long prev = ~0ull;
      for (int rd = 0; rd < K_; ++rd) {
        unsigned long long best = 0ull;
        for (int i = 0; i < 64; ++i) {
          int n = lane + 64*i;
          float4 v = rl[n];
          float c = fminf(1.f, fmaxf(-1.f, v.x*p.x + v.y*p.y + v.z*p.z));
          unsigned long long k = spack(c, n);
          if (k < prev && k > best) best = k;
        }
        #pragma unroll
        for (int off = 1; off < 64; off <<= 1) {
          unsigned long long o = shflxor64(best, off);
          best = o > best ? o : best;
        }
        if (lane == 0) selKey[r][rd] = best;
        prev = best;
      }
    } else {
      // 128-bin histogram select over candidates
      hist[r][lane] = 0u; hist[r][64 + lane] = 0u;
      const float inv = 127.999f / (1.000001f - th);
      for (unsigned base = 0; base < cn; base += 64) {
        unsigned it = base + lane;
        if (it < cn) {
          float c = key2f((unsigned)(cKey[r][it] >> 12));
          int bin = (int)((c - th) * inv);
          atomicAdd(&hist[r][bin], 1u);
        }
      }
      // suffix-sum over 128 bins (2/lane) -> threshold bin t, chi = cnt_gt(t)
      const int l = lane;
      unsigned hA = hist[r][2*l], hB = hist[r][2*l+1];
      unsigned g = hA + hB, s = g;
      #pragma unroll
      for (int off = 1; off < 64; off <<= 1) {
        unsigned t2 = (unsigned)__shfl_down((int)s, off);
        s += (l + off < 64) ? t2 : 0u;
      }
      unsigned snext = s - g;
      unsigned cB = hB + snext, cA = g + snext;
      unsigned packed = 0u;
      if      (cB >= K_) packed = ((unsigned)(2*l+2) << 16) | snext;
      else if (cA >= K_) packed = ((unsigned)(2*l+1) << 16) | cB;
      #pragma unroll
      for (int off = 32; off; off >>= 1) {
        unsigned o = (unsigned)__shfl_xor((int)packed, off);
        packed = packed > o ? packed : o;
      }
      const int t = (int)(packed >> 16) - 1;
      const unsigned chi = packed & 0xFFFFu;
      const unsigned need = K_ - chi;
      // collect winners (bin > t) + boundary (bin == t), ballot-compacted
      unsigned hiC = 0, bdC = 0;
      for (unsigned base = 0; base < cn; base += 64) {
        unsigned it = base + lane;
        bool act = it < cn;
        unsigned long long key = act ? cKey[r][it] : 0ull;
        int bin = -1;
        if (act) bin = (int)((key2f((unsigned)(key >> 12)) - th) * inv);
        bool pHi = act && bin > t;
        bool pBd = act && bin == t;
        unsigned long long mH = __ballot(pHi);
        unsigned offH = (unsigned)__popcll(mH & ltm);
        if (pHi && hiC + offH < K_) selKey[r][hiC + offH] = key;
        hiC += (unsigned)__popcll(mH);
        unsigned long long mB = __ballot(pBd);
        unsigned offB = (unsigned)__popcll(mB & ltm);
        if (pBd && bdC + offB < 16u) bnd[r][bdC + offB] = (int)it;
        bdC += (unsigned)__popcll(mB);
      }
      if (bdC <= 16u) {
        if (lane < (int)bdC) {
          unsigned long long ki = cKey[r][bnd[r][lane]];
          int rank = 0;
          for (int j = 0; j < (int)bdC; ++j) rank += (cKey[r][bnd[r][j]] > ki) ? 1 : 0;
          if ((unsigned)rank < need) selKey[r][chi + rank] = ki;
        }
      } else {
        // rare: rank-scan all candidates restricted to bin==t
        for (unsigned base = 0; base < cn; base += 64) {
          unsigned it = base + lane;
          if (it < cn) {
            unsigned long long ki = cKey[r][it];
            int bin = (int)((key2f((unsigned)(ki >> 12)) - th) * inv);
            if (bin == t) {
              int rank = 0;
              for (unsigned j = 0; j < cn; ++j) {
                unsigned long long kj = cKey[r][j];
                int bj = (int)((key2f((unsigned)(kj >> 12)) - th) * inv);
                rank += (bj == t && kj > ki) ? 1 : 0;
              }
              if ((unsigned)rank < need) selKey[r][chi + rank] = ki;
            }
          }
        }
      }
    }

    // attention MLP + softmax + weighted pool (lane = one winner; order-invariant)
    {
      unsigned long long key = selKey[r][lane];
      int n = 4095 - (int)(key & 0xFFFull);
      float c = key2f((unsigned)(key >> 12));
      float xg = rl[n].w;
      float d  = acosf(fminf(1.f, fmaxf(-1.f, c)));
      float acc = ab2[0];
      for (int s2 = 0; s2 < SH_; ++s2)
        acc += fmaxf(xg*aw1[s2] + d*aw1[SH_+s2] + ab1[s2], 0.f) * aw2[s2];
      float mx = acc;
      #pragma unroll
      for (int off = 32; off; off >>= 1) mx = fmaxf(mx, __shfl_xor(mx, off));
      float e = expf(acc - mx);
      float se = e, sxe = e * xg;
      #pragma unroll
      for (int off = 32; off; off >>= 1) { se += __shfl_xor(se, off); sxe += __shfl_xor(sxe, off); }
      if (lane == 0) pooled[b*M_ + m] = sxe / se;
    }
  }
}

// ---------------- knn v8: prefilter + exact top-8 ----------------
__global__ __launch_bounds__(512) void knn_v8(
    const float4* __restrict__ r_pix, const float* __restrict__ kthr, int* __restrict__ nbr)
{
  __shared__ float4 tile[2048];                    // 32 KB
  __shared__ unsigned long long cKey[KROWS][KCAP]; // 30 KB

  const int tid = threadIdx.x, wv = tid >> 6, lane = tid & 63;
  const int lr0 = wv*2;
  const int i0 = blockIdx.x*KROWS + lr0, i1 = i0 + 1;
  const float4 p0 = r_pix[i0], p1 = r_pix[i1];
  const float t0 = kthr[i0], t1 = kthr[i1];
  const unsigned long long ltm = (1ull << lane) - 1ull;

  unsigned cnt0 = 0, cnt1 = 0;
  for (int jt = 0; jt < M_; jt += 2048) {
    __syncthreads();
    #pragma unroll
    for (int q = 0; q < 4; ++q) tile[tid + 512*q] = r_pix[jt + tid + 512*q];
    __syncthreads();
    for (int g = 0; g < 32; ++g) {
      int jj = lane + 64*g;
      float4 v = tile[jj];
      int j = jt + jj;
      float s0 = 2.f*(p0.x*v.x + p0.y*v.y + p0.z*v.z) - v.w;
      float s1 = 2.f*(p1.x*v.x + p1.y*v.y + p1.z*v.z) - v.w;
      bool pr0 = (j != i0) && (s0 > t0);
      bool pr1 = (j != i1) && (s1 > t1);
      unsigned long long mk0 = __ballot(pr0);
      if (mk0) {
        unsigned off = (unsigned)__popcll(mk0 & ltm);
        if (pr0 && cnt0 + off < KCAP) cKey[lr0][cnt0 + off] = kpack(s0, j);
        cnt0 += (unsigned)__popcll(mk0);
      }
      unsigned long long mk1 = __ballot(pr1);
      if (mk1) {
        unsigned off = (unsigned)__popcll(mk1 & ltm);
        if (pr1 && cnt1 + off < KCAP) cKey[lr0+1][cnt1 + off] = kpack(s1, j);
        cnt1 += (unsigned)__popcll(mk1);
      }
    }
  }

  for (int rr = 0; rr < 2; ++rr) {
    const int lr = lr0 + rr;
    const int i  = i0 + rr;
    const float4 pi = (rr == 0) ? p0 : p1;
    float th = (rr == 0) ? t0 : t1;
    unsigned cn = (rr == 0) ? cnt0 : cnt1;

    int tries = 0;
    while (cn < (unsigned)GK_ && tries < 3) {
      th = 1.6f*th - 0.6f; ++tries;     // widen: s = 2cos-1, multiplicative in (1-cos)
      cn = 0;
      for (int j = lane; j < M_; j += 64) {
        float4 v = r_pix[j];
        float s = 2.f*(pi.x*v.x + pi.y*v.y + pi.z*v.z) - v.w;
        bool pr = (j != i) && (s > th);
        unsigned long long mk = __ballot(pr);
        if (mk) {
          unsigned off = (unsigned)__popcll(mk & ltm);
          if (pr && cn + off < KCAP) cKey[lr][cn + off] = kpack(s, j);
          cn += (unsigned)__popcll(mk);
        }
      }
    }

    if (cn >= (unsigned)GK_ && cn <= (unsigned)KCAP) {
      unsigned long long pk[4];
      #pragma unroll
      for (int t2 = 0; t2 < 4; ++t2) {
        int idx = lane + 64*t2;
        pk[t2] = (idx < (int)cn) ? cKey[lr][idx] : 0ull;
      }
      for (int round = 0; round < GK_; ++round) {
        unsigned long long loc = pk[0]; int lt = 0;
        #pragma unroll
        for (int t2 = 1; t2 < 4; ++t2) if (pk[t2] > loc) { loc = pk[t2]; lt = t2; }
        unsigned long long best = loc;
        #pragma unroll
        for (int off = 1; off < 64; off <<= 1) {
          unsigned long long o = shflxor64(best, off);
          best = o > best ? o : best;
        }
        if (loc == best) {
          #pragma unroll
          for (int t2 = 0; t2 < 4; ++t2) if (t2 == lt) pk[t2] = 0ull;
        }
        if (lane == round) nbr[i*GK_ + round] = 16383 - (int)(best & 16383ull);
      }
    } else {
      // ultimate exact: 8 rounds bounded argmax full scan
      unsigned long long prev = ~0ull;
      for (int rd = 0; rd < GK_; ++rd) {
        unsigned long long best = 0ull;
        for (int j = lane; j < M_; j += 64) {
          float4 v = r_pix[j];
          float s = 2.f*(pi.x*v.x + pi.y*v.y + pi.z*v.z) - v.w;
          if (j != i) {
            unsigned long long k = kpack(s, j);
            if (k < prev && k > best) best = k;
          }
        }
        #pragma unroll
        for (int off = 1; off < 64; off <<= 1) {
          unsigned long long o = shflxor64(best, off);
          best = o > best ? o : best;
        }
        if (lane == rd) nbr[i*GK_ + rd] = 16383 - (int)(best & 16383ull);
        prev = best;
      }
    }
  }
}

// ---------------- GNN layer 1 fused with proj (h0 is rank-1 in pooled) ----------------
__global__ __launch_bounds__(256) void gnn1f_v8(
    const float* __restrict__ pooled, float* __restrict__ hout, const int* __restrict__ nbr,
    const float* __restrict__ pw, const float* __restrict__ pb,
    const float* __restrict__ relw, const float* __restrict__ relb,
    const float* __restrict__ rootw)
{
  __shared__ float wrel[H_*H_], wroot[H_*H_];
  const int tid = threadIdx.x;
  #pragma unroll
  for (int q = 0; q < 16; ++q) {
    int idx = tid + 256*q;
    wrel[idx]  = relw[idx];
    wroot[idx] = rootw[idx];
  }
  __syncthreads();

  const int lane = tid & 63;
  const int wave = tid >> 6;
  const int b = blockIdx.y;
  const int m0 = blockIdx.x * 16 + wave * 4;
  const float* pldb = pooled + (size_t)b * M_;
  const float pwl = pw[lane], pbl = pb[lane], rbl = relb[lane];

  float h[4], agg[4], acc[4];
  #pragma unroll
  for (int t = 0; t < 4; ++t) {
    int m = m0 + t;
    float ps = pldb[m];
    h[t] = fmaxf(ps*pwl + pbl, 0.f);
    float a = 0.f;
    #pragma unroll
    for (int k = 0; k < GK_; ++k) {
      int nb = nbr[m*GK_ + k];
      nb = nb < 0 ? 0 : (nb >= M_ ? M_-1 : nb);
      float pn = pldb[nb];
      a += fmaxf(pn*pwl + pbl, 0.f);
    }
    agg[t] = a;
    acc[t] = rbl;
  }
  for (int c = 0; c < H_; ++c) {
    float wr = wrel[c*H_ + lane], wo = wroot[c*H_ + lane];
    #pragma unroll
    for (int t = 0; t < 4; ++t) {
      float a  = __shfl(agg[t], c);
      float hh = __shfl(h[t], c);
      acc[t] += a * wr + hh * wo;
    }
  }
  #pragma unroll
  for (int t = 0; t < 4; ++t)
    hout[((size_t)b*M_ + m0 + t)*H_ + lane] = fmaxf(acc[t], 0.f);
}

// ---------------- GNN layer (generic) ----------------
__global__ __launch_bounds__(256) void gnn_v8(
    const float* __restrict__ hin, float* __restrict__ hout, const int* __restrict__ nbr,
    const float* __restrict__ relw, const float* __restrict__ relb,
    const float* __restrict__ rootw)
{
  __shared__ float wrel[H_*H_], wroot[H_*H_], rb[H_];
  const int tid = threadIdx.x;
  #pragma unroll
  for (int q = 0; q < 16; ++q) {
    int idx = tid + 256*q;
    wrel[idx]  = relw[idx];
    wroot[idx] = rootw[idx];
  }
  if (tid < H_) rb[tid] = relb[tid];
  __syncthreads();

  const int lane = tid & 63;
  const int wave = tid >> 6;
  const int b = blockIdx.y;
  const int m0 = blockIdx.x * 16 + wave * 4;
  const float* hb = hin + (size_t)b * M_ * H_;

  float h[4], agg[4], acc[4];
  #pragma unroll
  for (int t = 0; t < 4; ++t) {
    int m = m0 + t;
    h[t] = hb[m*H_ + lane];
    float a = 0.f;
    #pragma unroll
    for (int k = 0; k < GK_; ++k) {
      int nb = nbr[m*GK_ + k];
      nb = nb < 0 ? 0 : (nb >= M_ ? M_-1 : nb);
      a += hb[nb*H_ + lane];
    }
    agg[t] = a;
    acc[t] = rb[lane];
  }
  for (int c = 0; c < H_; ++c) {
    float wr = wrel[c*H_ + lane], wo = wroot[c*H_ + lane];
    #pragma unroll
    for (int t = 0; t < 4; ++t) {
      float a  = __shfl(agg[t], c);
      float hh = __shfl(h[t], c);
      acc[t] += a * wr + hh * wo;
    }
  }
  #pragma unroll
  for (int t = 0; t < 4; ++t)
    hout[((size_t)b*M_ + m0 + t)*H_ + lane] = fmaxf(acc[t], 0.f);
}

// ---------------- reduce ----------------
__global__ __launch_bounds__(256) void reduce_v8(const float* __restrict__ h, float* __restrict__ gf)
{
  const int b = blockIdx.y;
  const int slice = blockIdx.x;
  const int c = threadIdx.x & 63, g = threadIdx.x >> 6;
  const float* hb = h + (size_t)b * M_ * H_;
  const int rows = M_ / 32;
  const int m0 = slice * rows;
  float s = 0.f;
  for (int r = g; r < rows; r += 4) s += hb[(m0 + r)*H_ + c];
  __shared__ float part[256];
  part[threadIdx.x] = s;
  __syncthreads();
  if (g == 0) {
    s = part[c] + part[64 + c] + part[128 + c] + part[192 + c];
    atomicAdd(&gf[b*H_ + c], s);
  }
}

// ---------------- head ----------------
__global__ __launch_bounds__(256) void head_v8(
    const float* __restrict__ gf, const float* __restrict__ w1,
    const float* __restrict__ b1, const float* __restrict__ w2,
    const float* __restrict__ b2, float* __restrict__ out)
{
  __shared__ float gfm[B_][H_], hid[B_][H_];
  const int tid = threadIdx.x;
  if (tid < B_*H_) gfm[tid >> 6][tid & 63] = gf[tid] * (1.f / (float)M_);
  __syncthreads();
  if (tid < B_*H_) {
    int b = tid >> 6, j = tid & 63;
    float acc = b1[j];
    for (int c = 0; c < H_; ++c) acc += gfm[b][c] * w1[c*H_ + j];
    hid[b][j] = fmaxf(acc, 0.f);
  }
  __syncthreads();
  for (int t = tid; t < B_*NC_; t += 256) {
    int b = t / NC_, o = t - b*NC_;
    float acc = b2[o];
    for (int j = 0; j < H_; ++j) acc += hid[b][j] * w2[j*NC_ + o];
    out[t] = acc;
  }
}

extern "C" void kernel_launch(void* const* d_in, const int* in_sizes, int n_in,
                              void* d_out, int out_size, void* d_ws, size_t ws_size,
                              hipStream_t stream)
{
  float* out = (float*)d_out;

  const size_t need = (size_t)M_*16 + (size_t)B_*N_*16 + (size_t)B_*M_*4
                    + (size_t)M_*GK_*4 + 2*(size_t)B_*M_*H_*4 + (size_t)B_*H_*4;
  bool ok_ws = ws_size >= need;
  bool ok_in = (n_in == 15) && (out_size == B_*NC_)
            && in_sizes[0] == B_*3*N_ && in_sizes[1] == M_*2
            && in_sizes[2] == 2*SH_ && in_sizes[5] == 1
            && in_sizes[8] == 3*H_*H_ && in_sizes[13] == H_*NC_;
  if (!ok_ws || !ok_in) {
    sentinel_v8<<<(out_size + 255)/256, 256, 0, stream>>>(out, out_size, ok_in ? 42.f : 43.f);
    return;
  }

  const float* xxx    = (const float*)d_in[0];
  const float* pix    = (const float*)d_in[1];
  const float* att_w1 = (const float*)d_in[2];
  const float* att_b1 = (const float*)d_in[3];
  const float* att_w2 = (const float*)d_in[4];
  const float* att_b2 = (const float*)d_in[5];
  const float* proj_w = (const float*)d_in[6];
  const float* proj_b = (const float*)d_in[7];
  const float* rel_w  = (const float*)d_in[8];
  const float* rel_b  = (const float*)d_in[9];
  const float* root_w = (const float*)d_in[10];
  const float* out_w1 = (const float*)d_in[11];
  const float* out_b1 = (const float*)d_in[12];
  const float* out_w2 = (const float*)d_in[13];
  const float* out_b2 = (const float*)d_in[14];

  char* w = (char*)d_ws;
  float4* r_pix = (float4*)w;  w += (size_t)M_ * 16;
  float4* r_los = (float4*)w;  w += (size_t)B_ * N_ * 16;
  float*  pooled = (float*)w;  w += (size_t)B_ * M_ * 4;
  int*    nbr = (int*)w;       w += (size_t)M_ * GK_ * 4;
  float*  h0 = (float*)w;      w += (size_t)B_ * M_ * H_ * 4;
  float*  h1 = (float*)w;      w += (size_t)B_ * M_ * H_ * 4;
  float*  gf = (float*)w;      w += (size_t)B_ * H_ * 4;
  // thresholds alias h0 (first written by gnn layer-2, after both consumers ran)
  float* kthr = h0;
  float* cthr = h0 + M_;

  prepthr_v8<<<THRB_ + PREPB_, 256, 0, stream>>>(xxx, pix, r_pix, r_los, gf, kthr, cthr);
  sampler_v8<<<dim3(M_/16, B_), 512, 0, stream>>>(r_pix, r_los, cthr, att_w1, att_b1, att_w2, att_b2, pooled);
  knn_v8<<<M_/KROWS, 512, 0, stream>>>(r_pix, kthr, nbr);
  gnn1f_v8<<<dim3(M_/16, B_), 256, 0, stream>>>(pooled, h1, nbr, proj_w, proj_b,
                                                rel_w + 0*H_*H_, rel_b + 0*H_, root_w + 0*H_*H_);
  gnn_v8<<<dim3(M_/16, B_), 256, 0, stream>>>(h1, h0, nbr, rel_w + 1*H_*H_, rel_b + 1*H_, root_w + 1*H_*H_);
  gnn_v8<<<dim3(M_/16, B_), 256, 0, stream>>>(h0, h1, nbr, rel_w + 2*H_*H_, rel_b + 2*H_, root_w + 2*H_*H_);
  reduce_v8<<<dim3(32, B_), 256, 0, stream>>>(h1, gf);
  head_v8<<<1, 256, 0, stream>>>(gf, out_w1, out_b1, out_w2, out_b2, out);
}

// Round 9
// 358.435 us; speedup vs baseline: 1.6254x; 1.3398x over previous
//
#include <hip/hip_runtime.h>
#include <hip/hip_bf16.h>

#define B_ 2
#define N_ 4096
#define M_ 12288
#define K_ 64
#define SH_ 32
#define H_ 64
#define GK_ 8
#define NC_ 200

#define SCAP 352       // sampler candidate cap (E=192)
#define KCAP 240       // knn candidate cap (E=128)
#define MG_ 0.01f      // theta-window safety margin (rad)
#define C256_ 81.48733086f   // 256/pi

static __device__ __forceinline__ unsigned f2key(float f) {
  unsigned b = __float_as_uint(f);
  return (b & 0x80000000u) ? ~b : (b | 0x80000000u);
}
static __device__ __forceinline__ float key2f(unsigned u) {
  unsigned b = (u & 0x80000000u) ? (u & 0x7fffffffu) : ~u;
  return __uint_as_float(b);
}
static __device__ __forceinline__ unsigned long long shflxor64(unsigned long long x, int m) {
  unsigned lo = (unsigned)x, hi = (unsigned)(x >> 32);
  lo = (unsigned)__shfl_xor((int)lo, m);
  hi = (unsigned)__shfl_xor((int)hi, m);
  return ((unsigned long long)hi << 32) | lo;
}
static __device__ __forceinline__ unsigned long long kpack(float s, int j) {
  return ((unsigned long long)f2key(s) << 14) | (unsigned)(16383 - j);
}
static __device__ __forceinline__ unsigned long long spack(float c, int n) {
  return ((unsigned long long)f2key(c) << 12) | (unsigned)(4095 - n);
}
static __device__ __forceinline__ int thbkt(float th) {
  int b = (int)(th * C256_);
  return b < 0 ? 0 : (b > 255 ? 255 : b);
}
static __device__ __forceinline__ float clamp1(float x) { return fminf(1.f, fmaxf(-1.f, x)); }

// ---------------- sentinel ----------------
__global__ __launch_bounds__(256) void sentinel_v9(float* out, int n, float val) {
  int t = blockIdx.x * 256 + threadIdx.x;
  if (t < n) out[t] = val;
}

// ---------------- prep + thresholds + zero counters ----------------
#define THRB_ 6144
#define PREPN_ (M_ + B_*N_ + B_*H_ + 768)
#define PREPB_ ((PREPN_ + 255)/256)

__global__ __launch_bounds__(256) void prepthr_v9(
    const float* __restrict__ xxx, const float* __restrict__ pix,
    float4* __restrict__ r_pix, float4* __restrict__ r_los, float* __restrict__ gf,
    float* __restrict__ kthr, float* __restrict__ cthr, unsigned* __restrict__ cnt)
{
  const float PI = 3.14159265358979f;
  if ((int)blockIdx.x < THRB_) {
    int gid  = blockIdx.x*4 + (threadIdx.x >> 6);
    int lane = threadIdx.x & 63;
    int tgt  = (gid >= M_) ? 1 : 0;
    int row  = gid - tgt*M_;
    float thp = pix[2*row];
    float cp = cosf(thp), sp = fmaxf(sinf(thp), 1e-6f);
    float thq = ((float)lane + 0.5f) * (PI/64.f);
    float sq = sinf(thq), cq = cosf(thq);
    float rinv = 1.0f / (sq * sp);
    float At = tgt ? (2.f*PI*PI*192.f/(float)N_) : (2.f*PI*PI*128.f/(float)M_);
    float lo = 1e-3f, hi = 3.1414f;
    for (int it = 0; it < 12; ++it) {
      float al = 0.5f*(lo + hi);
      float ca = cosf(al);
      float arg = clamp1((ca - cq*cp) * rinv);
      float ax = fabsf(arg);
      float ac = sqrtf(fmaxf(0.f, 1.f - ax)) *
                 fmaf(ax, fmaf(ax, fmaf(ax, -0.0187293f, 0.0742610f), -0.2121144f), 1.5707288f);
      ac = (arg < 0.f) ? (PI - ac) : ac;
      float S = ac;
      #pragma unroll
      for (int off = 32; off; off >>= 1) S += __shfl_xor(S, off);
      float A = 2.f * S * (PI/64.f);
      if (A < At) lo = al; else hi = al;
    }
    if (lane == 0) {
      float chv = cosf(hi);
      if (tgt) cthr[row] = chv - 1e-5f;
      else     kthr[row] = 2.f*chv - 1.00002f;
    }
  } else {
    int tid = ((int)blockIdx.x - THRB_)*256 + threadIdx.x;
    if (tid < M_) {
      float th = pix[2*tid], ph = pix[2*tid+1];
      float st = sinf(th);
      float x = st*cosf(ph), y = st*sinf(ph), z = cosf(th);
      r_pix[tid] = make_float4(x, y, z, x*x + y*y + z*z);
    }
    int t2 = tid - M_;
    if (t2 >= 0 && t2 < B_*N_) {
      int b = t2 >> 12, n = t2 & (N_-1);
      const float* xb = xxx + b*3*N_;
      float th = xb[n], ph = xb[N_+n], ft = xb[2*N_+n];
      float st = sinf(th);
      r_los[t2] = make_float4(st*cosf(ph), st*sinf(ph), cosf(th), ft);
    }
    int t3 = tid - M_ - B_*N_;
    if (t3 >= 0 && t3 < B_*H_) gf[t3] = 0.0f;
    int t4 = t3 - B_*H_;
    if (t4 >= 0 && t4 < 768) cnt[t4] = 0u;
  }
}

// ---------------- hist: theta-band histograms (pix + los per batch) ----------------
__global__ __launch_bounds__(256) void hist_v9(
    const float* __restrict__ xxx, const float* __restrict__ pix, unsigned* __restrict__ cnt)
{
  int tid = blockIdx.x * 256 + threadIdx.x;
  if (tid < M_) {
    atomicAdd(&cnt[thbkt(pix[2*tid])], 1u);
  } else {
    int t2 = tid - M_;
    if (t2 < B_*N_) {
      int b = t2 >> 12, n = t2 & (N_-1);
      atomicAdd(&cnt[256 + b*256 + thbkt(xxx[b*3*N_ + n])], 1u);
    }
  }
}

// ---------------- scan: exclusive prefix sums -> starts + cursors ----------------
__global__ __launch_bounds__(256) void scan_v9(
    const unsigned* __restrict__ cnt, int* __restrict__ pstart, int* __restrict__ lstart,
    unsigned* __restrict__ pcur, unsigned* __restrict__ lcur)
{
  __shared__ unsigned buf[256];
  const int t = threadIdx.x;
  for (int arr = 0; arr < 3; ++arr) {
    unsigned v = cnt[arr*256 + t];
    buf[t] = v;
    __syncthreads();
    for (int off = 1; off < 256; off <<= 1) {
      unsigned o = (t >= off) ? buf[t - off] : 0u;
      __syncthreads();
      buf[t] += o;
      __syncthreads();
    }
    unsigned incl = buf[t], excl = incl - v;
    if (arr == 0) {
      pstart[t] = (int)excl; if (t == 255) pstart[256] = (int)incl;
      pcur[t] = excl;
    } else {
      int b = arr - 1;
      lstart[b*257 + t] = (int)excl; if (t == 255) lstart[b*257 + 256] = (int)incl;
      lcur[b*256 + t] = excl;
    }
    __syncthreads();
  }
}

// ---------------- scatter: counting-sort by theta band ----------------
__global__ __launch_bounds__(256) void scatter_v9(
    const float* __restrict__ xxx, const float* __restrict__ pix,
    const float4* __restrict__ r_pix, const float4* __restrict__ r_los,
    unsigned* __restrict__ pcur, unsigned* __restrict__ lcur,
    float4* __restrict__ spix, int* __restrict__ sjdx,
    float4* __restrict__ slos, int* __restrict__ sldx)
{
  int tid = blockIdx.x * 256 + threadIdx.x;
  if (tid < M_) {
    int bkt = thbkt(pix[2*tid]);
    unsigned pos = atomicAdd(&pcur[bkt], 1u);
    spix[pos] = r_pix[tid];
    sjdx[pos] = tid;
  } else {
    int t2 = tid - M_;
    if (t2 < B_*N_) {
      int b = t2 >> 12, n = t2 & (N_-1);
      int bkt = thbkt(xxx[b*3*N_ + n]);
      unsigned pos = atomicAdd(&lcur[b*256 + bkt], 1u);
      slos[b*N_ + pos] = r_los[t2];
      sldx[b*N_ + pos] = n;
    }
  }
}

// ---------------- sampler v9: theta-window prefilter + 128-bin select ----------------
__global__ __launch_bounds__(512) void sampler_v9(
    const float* __restrict__ pix,
    const float4* __restrict__ spix, const int* __restrict__ sjdx,
    const float4* __restrict__ slos, const int* __restrict__ sldx,
    const int* __restrict__ lstart, const float4* __restrict__ r_los,
    const float* __restrict__ cthr,
    const float* __restrict__ aw1, const float* __restrict__ ab1,
    const float* __restrict__ aw2, const float* __restrict__ ab2,
    float* __restrict__ pooled)
{
  __shared__ unsigned long long cKey[16][SCAP];
  __shared__ unsigned long long selKey[16][K_];
  __shared__ unsigned hist[16][128];
  __shared__ int bnd[16][16];

  const int tid = threadIdx.x, wv = tid >> 6, lane = tid & 63;
  const int b  = blockIdx.y;
  const int srow0 = blockIdx.x*16 + wv*2, srow1 = srow0 + 1;
  const int r0 = wv*2, r1 = r0 + 1;
  const int m0 = sjdx[srow0], m1 = sjdx[srow1];
  const float4 p0 = spix[srow0], p1 = spix[srow1];
  const float thp0 = pix[2*m0], thp1 = pix[2*m1];
  float th0 = cthr[m0], th1 = cthr[m1];
  const float4* sl = slos + b * N_;
  const int* sx = sldx + b * N_;
  const float4* rl = r_los + b * N_;
  const int* ls = lstart + b * 257;
  const unsigned long long ltm = (1ull << lane) - 1ull;

  // phase A: union theta-window scan, both rows per load
  unsigned cnt0 = 0, cnt1 = 0;
  {
    float al0 = acosf(clamp1(th0)), al1 = acosf(clamp1(th1));
    int blo = thbkt(fminf(thp0 - al0, thp1 - al1) - MG_);
    int bhi = thbkt(fmaxf(thp0 + al0, thp1 + al1) + MG_);
    int jlo = ls[blo], jhi = ls[bhi + 1];
    for (int base = jlo; base < jhi; base += 64) {
      int pos = base + lane;
      bool act = pos < jhi;
      float c0 = -2.f, c1 = -2.f; int n = 0;
      if (act) {
        float4 v = sl[pos]; n = sx[pos];
        c0 = clamp1(v.x*p0.x + v.y*p0.y + v.z*p0.z);
        c1 = clamp1(v.x*p1.x + v.y*p1.y + v.z*p1.z);
      }
      bool pr0 = c0 > th0, pr1 = c1 > th1;
      unsigned long long mk0 = __ballot(pr0);
      if (mk0) {
        unsigned off = (unsigned)__popcll(mk0 & ltm);
        if (pr0 && cnt0 + off < SCAP) cKey[r0][cnt0 + off] = spack(c0, n);
        cnt0 += (unsigned)__popcll(mk0);
      }
      unsigned long long mk1 = __ballot(pr1);
      if (mk1) {
        unsigned off = (unsigned)__popcll(mk1 & ltm);
        if (pr1 && cnt1 + off < SCAP) cKey[r1][cnt1 + off] = spack(c1, n);
        cnt1 += (unsigned)__popcll(mk1);
      }
    }
  }

  for (int rr = 0; rr < 2; ++rr) {
    const int r = (rr == 0) ? r0 : r1;
    const int m = (rr == 0) ? m0 : m1;
    const float4 p = (rr == 0) ? p0 : p1;
    const float thp = (rr == 0) ? thp0 : thp1;
    float th = (rr == 0) ? th0 : th1;
    unsigned cn = (rr == 0) ? cnt0 : cnt1;

    int tries = 0;
    while (cn < K_ && tries < 3) {
      th = 1.f - 1.6f*(1.f - th); ++tries;
      float al = acosf(clamp1(th));
      int blo = thbkt(thp - al - MG_), bhi = thbkt(thp + al + MG_);
      int jlo = ls[blo], jhi = ls[bhi + 1];
      cn = 0;
      for (int base = jlo; base < jhi; base += 64) {
        int pos = base + lane;
        bool act = pos < jhi;
        float c = -2.f; int n = 0;
        if (act) {
          float4 v = sl[pos]; n = sx[pos];
          c = clamp1(v.x*p.x + v.y*p.y + v.z*p.z);
        }
        bool pr = c > th;
        unsigned long long mk = __ballot(pr);
        if (mk) {
          unsigned off = (unsigned)__popcll(mk & ltm);
          if (pr && cn + off < SCAP) cKey[r][cn + off] = spack(c, n);
          cn += (unsigned)__popcll(mk);
        }
      }
    }

    if (cn < K_ || cn > SCAP) {
      // ultimate exact: 64 rounds bounded argmax over full row
      unsigned long long prev = ~0ull;
      for (int rd = 0; rd < K_; ++rd) {
        unsigned long long best = 0ull;
        for (int i = 0; i < 64; ++i) {
          int n = lane + 64*i;
          float4 v = rl[n];
          float c = clamp1(v.x*p.x + v.y*p.y + v.z*p.z);
          unsigned long long k = spack(c, n);
          if (k < prev && k > best) best = k;
        }
        #pragma unroll
        for (int off = 1; off < 64; off <<= 1) {
          unsigned long long o = shflxor64(best, off);
          best = o > best ? o : best;
        }
        if (lane == 0) selKey[r][rd] = best;
        prev = best;
      }
    } else {
      hist[r][lane] = 0u; hist[r][64 + lane] = 0u;
      const float inv = 127.999f / (1.000001f - th);
      for (unsigned base = 0; base < cn; base += 64) {
        unsigned it = base + lane;
        if (it < cn) {
          float c = key2f((unsigned)(cKey[r][it] >> 12));
          int bin = (int)((c - th) * inv);
          atomicAdd(&hist[r][bin], 1u);
        }
      }
      const int l = lane;
      unsigned hA = hist[r][2*l], hB = hist[r][2*l+1];
      unsigned g = hA + hB, s = g;
      #pragma unroll
      for (int off = 1; off < 64; off <<= 1) {
        unsigned t2 = (unsigned)__shfl_down((int)s, off);
        s += (l + off < 64) ? t2 : 0u;
      }
      unsigned snext = s - g;
      unsigned cB = hB + snext, cA = g + snext;
      unsigned packed = 0u;
      if      (cB >= K_) packed = ((unsigned)(2*l+2) << 16) | snext;
      else if (cA >= K_) packed = ((unsigned)(2*l+1) << 16) | cB;
      #pragma unroll
      for (int off = 32; off; off >>= 1) {
        unsigned o = (unsigned)__shfl_xor((int)packed, off);
        packed = packed > o ? packed : o;
      }
      const int t = (int)(packed >> 16) - 1;
      const unsigned chi = packed & 0xFFFFu;
      const unsigned need = K_ - chi;
      unsigned hiC = 0, bdC = 0;
      for (unsigned base = 0; base < cn; base += 64) {
        unsigned it = base + lane;
        bool act = it < cn;
        unsigned long long key = act ? cKey[r][it] : 0ull;
        int bin = -1;
        if (act) bin = (int)((key2f((unsigned)(key >> 12)) - th) * inv);
        bool pHi = act && bin > t;
        bool pBd = act && bin == t;
        unsigned long long mH = __ballot(pHi);
        unsigned offH = (unsigned)__popcll(mH & ltm);
        if (pHi && hiC + offH < K_) selKey[r][hiC + offH] = key;
        hiC += (unsigned)__popcll(mH);
        unsigned long long mB = __ballot(pBd);
        unsigned offB = (unsigned)__popcll(mB & ltm);
        if (pBd && bdC + offB < 16u) bnd[r][bdC + offB] = (int)it;
        bdC += (unsigned)__popcll(mB);
      }
      if (bdC <= 16u) {
        if (lane < (int)bdC) {
          unsigned long long ki = cKey[r][bnd[r][lane]];
          int rank = 0;
          for (int j = 0; j < (int)bdC; ++j) rank += (cKey[r][bnd[r][j]] > ki) ? 1 : 0;
          if ((unsigned)rank < need) selKey[r][chi + rank] = ki;
        }
      } else {
        for (unsigned base = 0; base < cn; base += 64) {
          unsigned it = base + lane;
          if (it < cn) {
            unsigned long long ki = cKey[r][it];
            int bin = (int)((key2f((unsigned)(ki >> 12)) - th) * inv);
            if (bin == t) {
              int rank = 0;
              for (unsigned j = 0; j < cn; ++j) {
                unsigned long long kj = cKey[r][j];
                int bj = (int)((key2f((unsigned)(kj >> 12)) - th) * inv);
                rank += (bj == t && kj > ki) ? 1 : 0;
              }
              if ((unsigned)rank < need) selKey[r][chi + rank] = ki;
            }
          }
        }
      }
    }

    // attention MLP + softmax + weighted pool
    {
      unsigned long long key = selKey[r][lane];
      int n = 4095 - (int)(key & 0xFFFull);
      float c = key2f((unsigned)(key >> 12));
      float xg = rl[n].w;
      float d  = acosf(clamp1(c));
      float acc = ab2[0];
      for (int s2 = 0; s2 < SH_; ++s2)
        acc += fmaxf(xg*aw1[s2] + d*aw1[SH_+s2] + ab1[s2], 0.f) * aw2[s2];
      float mx = acc;
      #pragma unroll
      for (int off = 32; off; off >>= 1) mx = fmaxf(mx, __shfl_xor(mx, off));
      float e = expf(acc - mx);
      float se = e, sxe = e * xg;
      #pragma unroll
      for (int off = 32; off; off >>= 1) { se += __shfl_xor(se, off); sxe += __shfl_xor(sxe, off); }
      if (lane == 0) pooled[b*M_ + m] = sxe / se;
    }
  }
}

// ---------------- knn v9: theta-window prefilter + exact top-8 ----------------
__global__ __launch_bounds__(512) void knn_v9(
    const float* __restrict__ pix,
    const float4* __restrict__ spix, const int* __restrict__ sjdx,
    const int* __restrict__ pstart, const float4* __restrict__ r_pix,
    const float* __restrict__ kthr, int* __restrict__ nbr)
{
  __shared__ unsigned long long cKey[16][KCAP];   // 30 KB

  const int tid = threadIdx.x, wv = tid >> 6, lane = tid & 63;
  const int lr0 = wv*2;
  const int srow0 = blockIdx.x*16 + lr0, srow1 = srow0 + 1;
  const int i0 = sjdx[srow0], i1 = sjdx[srow1];
  const float4 p0 = spix[srow0], p1 = spix[srow1];
  const float thp0 = pix[2*i0], thp1 = pix[2*i1];
  const float t0 = kthr[i0], t1 = kthr[i1];
  const unsigned long long ltm = (1ull << lane) - 1ull;

  unsigned cnt0 = 0, cnt1 = 0;
  {
    float al0 = acosf(clamp1((t0 + 1.00002f)*0.5f));
    float al1 = acosf(clamp1((t1 + 1.00002f)*0.5f));
    int blo = thbkt(fminf(thp0 - al0, thp1 - al1) - MG_);
    int bhi = thbkt(fmaxf(thp0 + al0, thp1 + al1) + MG_);
    int jlo = pstart[blo], jhi = pstart[bhi + 1];
    for (int base = jlo; base < jhi; base += 64) {
      int pos = base + lane;
      bool act = pos < jhi;
      float s0 = -1e30f, s1 = -1e30f; int j = -1;
      if (act) {
        float4 v = spix[pos]; j = sjdx[pos];
        s0 = 2.f*(p0.x*v.x + p0.y*v.y + p0.z*v.z) - v.w;
        s1 = 2.f*(p1.x*v.x + p1.y*v.y + p1.z*v.z) - v.w;
      }
      bool pr0 = act && (j != i0) && (s0 > t0);
      bool pr1 = act && (j != i1) && (s1 > t1);
      unsigned long long mk0 = __ballot(pr0);
      if (mk0) {
        unsigned off = (unsigned)__popcll(mk0 & ltm);
        if (pr0 && cnt0 + off < KCAP) cKey[lr0][cnt0 + off] = kpack(s0, j);
        cnt0 += (unsigned)__popcll(mk0);
      }
      unsigned long long mk1 = __ballot(pr1);
      if (mk1) {
        unsigned off = (unsigned)__popcll(mk1 & ltm);
        if (pr1 && cnt1 + off < KCAP) cKey[lr0+1][cnt1 + off] = kpack(s1, j);
        cnt1 += (unsigned)__popcll(mk1);
      }
    }
  }

  for (int rr = 0; rr < 2; ++rr) {
    const int lr = lr0 + rr;
    const int i  = (rr == 0) ? i0 : i1;
    const float4 pi = (rr == 0) ? p0 : p1;
    const float thp = (rr == 0) ? thp0 : thp1;
    float th = (rr == 0) ? t0 : t1;
    unsigned cn = (rr == 0) ? cnt0 : cnt1;

    int tries = 0;
    while (cn < (unsigned)GK_ && tries < 3) {
      th = 1.6f*th - 0.6f; ++tries;
      float al = acosf(clamp1((th + 1.00002f)*0.5f));
      int blo = thbkt(thp - al - MG_), bhi = thbkt(thp + al + MG_);
      int jlo = pstart[blo], jhi = pstart[bhi + 1];
      cn = 0;
      for (int base = jlo; base < jhi; base += 64) {
        int pos = base + lane;
        bool act = pos < jhi;
        float s = -1e30f; int j = -1;
        if (act) {
          float4 v = spix[pos]; j = sjdx[pos];
          s = 2.f*(pi.x*v.x + pi.y*v.y + pi.z*v.z) - v.w;
        }
        bool pr = act && (j != i) && (s > th);
        unsigned long long mk = __ballot(pr);
        if (mk) {
          unsigned off = (unsigned)__popcll(mk & ltm);
          if (pr && cn + off < KCAP) cKey[lr][cn + off] = kpack(s, j);
          cn += (unsigned)__popcll(mk);
        }
      }
    }

    if (cn >= (unsigned)GK_ && cn <= (unsigned)KCAP) {
      unsigned long long pk[4];
      #pragma unroll
      for (int t2 = 0; t2 < 4; ++t2) {
        int idx = lane + 64*t2;
        pk[t2] = (idx < (int)cn) ? cKey[lr][idx] : 0ull;
      }
      for (int round = 0; round < GK_; ++round) {
        unsigned long long loc = pk[0]; int lt = 0;
        #pragma unroll
        for (int t2 = 1; t2 < 4; ++t2) if (pk[t2] > loc) { loc = pk[t2]; lt = t2; }
        unsigned long long best = loc;
        #pragma unroll
        for (int off = 1; off < 64; off <<= 1) {
          unsigned long long o = shflxor64(best, off);
          best = o > best ? o : best;
        }
        if (loc == best) {
          #pragma unroll
          for (int t2 = 0; t2 < 4; ++t2) if (t2 == lt) pk[t2] = 0ull;
        }
        if (lane == round) nbr[i*GK_ + round] = 16383 - (int)(best & 16383ull);
      }
    } else {
      unsigned long long prev = ~0ull;
      for (int rd = 0; rd < GK_; ++rd) {
        unsigned long long best = 0ull;
        for (int j = lane; j < M_; j += 64) {
          float4 v = r_pix[j];
          float s = 2.f*(pi.x*v.x + pi.y*v.y + pi.z*v.z) - v.w;
          if (j != i) {
            unsigned long long k = kpack(s, j);
            if (k < prev && k > best) best = k;
          }
        }
        #pragma unroll
        for (int off = 1; off < 64; off <<= 1) {
          unsigned long long o = shflxor64(best, off);
          best = o > best ? o : best;
        }
        if (lane == rd) nbr[i*GK_ + rd] = 16383 - (int)(best & 16383ull);
        prev = best;
      }
    }
  }
}

// ---------------- GNN layer 1 fused with proj ----------------
__global__ __launch_bounds__(256) void gnn1f_v9(
    const float* __restrict__ pooled, float* __restrict__ hout, const int* __restrict__ nbr,
    const float* __restrict__ pw, const float* __restrict__ pb,
    const float* __restrict__ relw, const float* __restrict__ relb,
    const float* __restrict__ rootw)
{
  __shared__ float wrel[H_*H_], wroot[H_*H_];
  const int tid = threadIdx.x;
  #pragma unroll
  for (int q = 0; q < 16; ++q) {
    int idx = tid + 256*q;
    wrel[idx]  = relw[idx];
    wroot[idx] = rootw[idx];
  }
  __syncthreads();

  const int lane = tid & 63;
  const int wave = tid >> 6;
  const int b = blockIdx.y;
  const int m0 = blockIdx.x * 16 + wave * 4;
  const float* pldb = pooled + (size_t)b * M_;
  const float pwl = pw[lane], pbl = pb[lane], rbl = relb[lane];

  float h[4], agg[4], acc[4];
  #pragma unroll
  for (int t = 0; t < 4; ++t) {
    int m = m0 + t;
    float ps = pldb[m];
    h[t] = fmaxf(ps*pwl + pbl, 0.f);
    float a = 0.f;
    #pragma unroll
    for (int k = 0; k < GK_; ++k) {
      int nb = nbr[m*GK_ + k];
      nb = nb < 0 ? 0 : (nb >= M_ ? M_-1 : nb);
      float pn = pldb[nb];
      a += fmaxf(pn*pwl + pbl, 0.f);
    }
    agg[t] = a;
    acc[t] = rbl;
  }
  for (int c = 0; c < H_; ++c) {
    float wr = wrel[c*H_ + lane], wo = wroot[c*H_ + lane];
    #pragma unroll
    for (int t = 0; t < 4; ++t) {
      float a  = __shfl(agg[t], c);
      float hh = __shfl(h[t], c);
      acc[t] += a * wr + hh * wo;
    }
  }
  #pragma unroll
  for (int t = 0; t < 4; ++t)
    hout[((size_t)b*M_ + m0 + t)*H_ + lane] = fmaxf(acc[t], 0.f);
}

// ---------------- GNN layer (generic) ----------------
__global__ __launch_bounds__(256) void gnn_v9(
    const float* __restrict__ hin, float* __restrict__ hout, const int* __restrict__ nbr,
    const float* __restrict__ relw, const float* __restrict__ relb,
    const float* __restrict__ rootw)
{
  __shared__ float wrel[H_*H_], wroot[H_*H_], rb[H_];
  const int tid = threadIdx.x;
  #pragma unroll
  for (int q = 0; q < 16; ++q) {
    int idx = tid + 256*q;
    wrel[idx]  = relw[idx];
    wroot[idx] = rootw[idx];
  }
  if (tid < H_) rb[tid] = relb[tid];
  __syncthreads();

  const int lane = tid & 63;
  const int wave = tid >> 6;
  const int b = blockIdx.y;
  const int m0 = blockIdx.x * 16 + wave * 4;
  const float* hb = hin + (size_t)b * M_ * H_;

  float h[4], agg[4], acc[4];
  #pragma unroll
  for (int t = 0; t < 4; ++t) {
    int m = m0 + t;
    h[t] = hb[m*H_ + lane];
    float a = 0.f;
    #pragma unroll
    for (int k = 0; k < GK_; ++k) {
      int nb = nbr[m*GK_ + k];
      nb = nb < 0 ? 0 : (nb >= M_ ? M_-1 : nb);
      a += hb[nb*H_ + lane];
    }
    agg[t] = a;
    acc[t] = rb[lane];
  }
  for (int c = 0; c < H_; ++c) {
    float wr = wrel[c*H_ + lane], wo = wroot[c*H_ + lane];
    #pragma unroll
    for (int t = 0; t < 4; ++t) {
      float a  = __shfl(agg[t], c);
      float hh = __shfl(h[t], c);
      acc[t] += a * wr + hh * wo;
    }
  }
  #pragma unroll
  for (int t = 0; t < 4; ++t)
    hout[((size_t)b*M_ + m0 + t)*H_ + lane] = fmaxf(acc[t], 0.f);
}

// ---------------- reduce ----------------
__global__ __launch_bounds__(256) void reduce_v9(const float* __restrict__ h, float* __restrict__ gf)
{
  const int b = blockIdx.y;
  const int slice = blockIdx.x;
  const int c = threadIdx.x & 63, g = threadIdx.x >> 6;
  const float* hb = h + (size_t)b * M_ * H_;
  const int rows = M_ / 32;
  const int m0 = slice * rows;
  float s = 0.f;
  for (int r = g; r < rows; r += 4) s += hb[(m0 + r)*H_ + c];
  __shared__ float part[256];
  part[threadIdx.x] = s;
  __syncthreads();
  if (g == 0) {
    s = part[c] + part[64 + c] + part[128 + c] + part[192 + c];
    atomicAdd(&gf[b*H_ + c], s);
  }
}

// ---------------- head ----------------
__global__ __launch_bounds__(256) void head_v9(
    const float* __restrict__ gf, const float* __restrict__ w1,
    const float* __restrict__ b1, const float* __restrict__ w2,
    const float* __restrict__ b2, float* __restrict__ out)
{
  __shared__ float gfm[B_][H_], hid[B_][H_];
  const int tid = threadIdx.x;
  if (tid < B_*H_) gfm[tid >> 6][tid & 63] = gf[tid] * (1.f / (float)M_);
  __syncthreads();
  if (tid < B_*H_) {
    int b = tid >> 6, j = tid & 63;
    float acc = b1[j];
    for (int c = 0; c < H_; ++c) acc += gfm[b][c] * w1[c*H_ + j];
    hid[b][j] = fmaxf(acc, 0.f);
  }
  __syncthreads();
  for (int t = tid; t < B_*NC_; t += 256) {
    int b = t / NC_, o = t - b*NC_;
    float acc = b2[o];
    for (int j = 0; j < H_; ++j) acc += hid[b][j] * w2[j*NC_ + o];
    out[t] = acc;
  }
}

extern "C" void kernel_launch(void* const* d_in, const int* in_sizes, int n_in,
                              void* d_out, int out_size, void* d_ws, size_t ws_size,
                              hipStream_t stream)
{
  float* out = (float*)d_out;

  const size_t need = (size_t)M_*16 + (size_t)B_*N_*16 + (size_t)B_*M_*4
                    + (size_t)M_*GK_*4 + 2*(size_t)B_*M_*H_*4 + (size_t)B_*H_*4;
  bool ok_ws = ws_size >= need;
  bool ok_in = (n_in == 15) && (out_size == B_*NC_)
            && in_sizes[0] == B_*3*N_ && in_sizes[1] == M_*2
            && in_sizes[2] == 2*SH_ && in_sizes[5] == 1
            && in_sizes[8] == 3*H_*H_ && in_sizes[13] == H_*NC_;
  if (!ok_ws || !ok_in) {
    sentinel_v9<<<(out_size + 255)/256, 256, 0, stream>>>(out, out_size, ok_in ? 42.f : 43.f);
    return;
  }

  const float* xxx    = (const float*)d_in[0];
  const float* pix    = (const float*)d_in[1];
  const float* att_w1 = (const float*)d_in[2];
  const float* att_b1 = (const float*)d_in[3];
  const float* att_w2 = (const float*)d_in[4];
  const float* att_b2 = (const float*)d_in[5];
  const float* proj_w = (const float*)d_in[6];
  const float* proj_b = (const float*)d_in[7];
  const float* rel_w  = (const float*)d_in[8];
  const float* rel_b  = (const float*)d_in[9];
  const float* root_w = (const float*)d_in[10];
  const float* out_w1 = (const float*)d_in[11];
  const float* out_b1 = (const float*)d_in[12];
  const float* out_w2 = (const float*)d_in[13];
  const float* out_b2 = (const float*)d_in[14];

  char* w = (char*)d_ws;
  float4* r_pix = (float4*)w;  w += (size_t)M_ * 16;
  float4* r_los = (float4*)w;  w += (size_t)B_ * N_ * 16;
  float*  pooled = (float*)w;  w += (size_t)B_ * M_ * 4;
  int*    nbr = (int*)w;       w += (size_t)M_ * GK_ * 4;
  float*  h0 = (float*)w;      w += (size_t)B_ * M_ * H_ * 4;
  float*  h1 = (float*)w;      w += (size_t)B_ * M_ * H_ * 4;
  float*  gf = (float*)w;      w += (size_t)B_ * H_ * 4;

  // sort/threshold scratch aliases h0 (dead until gnn layer 2 writes it)
  float*  kthr = h0;                                   // M
  float*  cthr = h0 + M_;                              // M
  float4* spix = (float4*)(h0 + 2*M_);                 // M float4
  int*    sjdx = (int*)(h0 + 6*M_);                    // M
  float4* slos = (float4*)(h0 + 7*M_);                 // B*N float4
  int*    sldx = (int*)(h0 + 7*M_ + 4*B_*N_);          // B*N
  unsigned* cnt = (unsigned*)(h0 + 7*M_ + 5*B_*N_);    // 768
  int*    pstart = (int*)(cnt + 768);                  // 257
  int*    lstart = pstart + 257;                       // 2*257
  unsigned* pcur = (unsigned*)(lstart + 514);          // 256
  unsigned* lcur = pcur + 256;                         // 512

  prepthr_v9<<<THRB_ + PREPB_, 256, 0, stream>>>(xxx, pix, r_pix, r_los, gf, kthr, cthr, cnt);
  hist_v9<<<(M_ + B_*N_ + 255)/256, 256, 0, stream>>>(xxx, pix, cnt);
  scan_v9<<<1, 256, 0, stream>>>(cnt, pstart, lstart, pcur, lcur);
  scatter_v9<<<(M_ + B_*N_ + 255)/256, 256, 0, stream>>>(xxx, pix, r_pix, r_los, pcur, lcur,
                                                         spix, sjdx, slos, sldx);
  sampler_v9<<<dim3(M_/16, B_), 512, 0, stream>>>(pix, spix, sjdx, slos, sldx, lstart, r_los,
                                                  cthr, att_w1, att_b1, att_w2, att_b2, pooled);
  knn_v9<<<M_/16, 512, 0, stream>>>(pix, spix, sjdx, pstart, r_pix, kthr, nbr);
  gnn1f_v9<<<dim3(M_/16, B_), 256, 0, stream>>>(pooled, h1, nbr, proj_w, proj_b,
                                                rel_w + 0*H_*H_, rel_b + 0*H_, root_w + 0*H_*H_);
  gnn_v9<<<dim3(M_/16, B_), 256, 0, stream>>>(h1, h0, nbr, rel_w + 1*H_*H_, rel_b + 1*H_, root_w + 1*H_*H_);
  gnn_v9<<<dim3(M_/16, B_), 256, 0, stream>>>(h0, h1, nbr, rel_w + 2*H_*H_, rel_b + 2*H_, root_w + 2*H_*H_);
  reduce_v9<<<dim3(32, B_), 256, 0, stream>>>(h1, gf);
  head_v9<<<1, 256, 0, stream>>>(gf, out_w1, out_b1, out_w2, out_b2, out);
}

// Round 10
// 275.260 us; speedup vs baseline: 2.1166x; 1.3022x over previous
//
#include <hip/hip_runtime.h>
#include <hip/hip_bf16.h>

#define B_ 2
#define N_ 4096
#define M_ 12288
#define K_ 64
#define SH_ 32
#define H_ 64
#define GK_ 8
#define NC_ 200

#define SCAP 288       // sampler candidate cap (E=192, +6.9 sigma)
#define KCAP 240       // knn candidate cap (E=128)
#define MG_ 0.01f      // theta-window safety margin (rad)
#define C256_ 81.48733086f   // 256/pi

static __device__ __forceinline__ unsigned f2key(float f) {
  unsigned b = __float_as_uint(f);
  return (b & 0x80000000u) ? ~b : (b | 0x80000000u);
}
static __device__ __forceinline__ float key2f(unsigned u) {
  unsigned b = (u & 0x80000000u) ? (u & 0x7fffffffu) : ~u;
  return __uint_as_float(b);
}
static __device__ __forceinline__ unsigned long long shflxor64(unsigned long long x, int m) {
  unsigned lo = (unsigned)x, hi = (unsigned)(x >> 32);
  lo = (unsigned)__shfl_xor((int)lo, m);
  hi = (unsigned)__shfl_xor((int)hi, m);
  return ((unsigned long long)hi << 32) | lo;
}
static __device__ __forceinline__ unsigned long long kpack(float s, int j) {
  return ((unsigned long long)f2key(s) << 14) | (unsigned)(16383 - j);
}
static __device__ __forceinline__ unsigned long long spack(float c, int n) {
  return ((unsigned long long)f2key(c) << 12) | (unsigned)(4095 - n);
}
static __device__ __forceinline__ int thbkt(float th) {
  int b = (int)(th * C256_);
  return b < 0 ? 0 : (b > 255 ? 255 : b);
}
static __device__ __forceinline__ float clamp1(float x) { return fminf(1.f, fmaxf(-1.f, x)); }
static __device__ __forceinline__ float rdlane(float v, int c) {
  return __uint_as_float((unsigned)__builtin_amdgcn_readlane((int)__float_as_uint(v), c));
}

// ---------------- sentinel ----------------
__global__ __launch_bounds__(256) void sentinel_vA(float* out, int n, float val) {
  int t = blockIdx.x * 256 + threadIdx.x;
  if (t < n) out[t] = val;
}

// ---------------- prep + thresholds + theta-band histograms ----------------
#define THRB_ 6144
#define PREPN_ (M_ + B_*N_ + B_*H_)
#define PREPB_ ((PREPN_ + 255)/256)

__global__ __launch_bounds__(256) void prepthr_vA(
    const float* __restrict__ xxx, const float* __restrict__ pix,
    float4* __restrict__ r_pix, float4* __restrict__ r_los, float* __restrict__ gf,
    float* __restrict__ kthr, float* __restrict__ cthr, unsigned* __restrict__ cnt)
{
  const float PI = 3.14159265358979f;
  if ((int)blockIdx.x < THRB_) {
    int gid  = blockIdx.x*4 + (threadIdx.x >> 6);
    int lane = threadIdx.x & 63;
    int tgt  = (gid >= M_) ? 1 : 0;
    int row  = gid - tgt*M_;
    float thp = pix[2*row];
    float cp = cosf(thp), sp = fmaxf(sinf(thp), 1e-6f);
    float thq = ((float)lane + 0.5f) * (PI/64.f);
    float sq = sinf(thq), cq = cosf(thq);
    float rinv = 1.0f / (sq * sp);
    float At = tgt ? (2.f*PI*PI*192.f/(float)N_) : (2.f*PI*PI*128.f/(float)M_);
    float lo = 1e-3f, hi = 3.1414f;
    for (int it = 0; it < 12; ++it) {
      float al = 0.5f*(lo + hi);
      float ca = cosf(al);
      float arg = clamp1((ca - cq*cp) * rinv);
      float ax = fabsf(arg);
      float ac = sqrtf(fmaxf(0.f, 1.f - ax)) *
                 fmaf(ax, fmaf(ax, fmaf(ax, -0.0187293f, 0.0742610f), -0.2121144f), 1.5707288f);
      ac = (arg < 0.f) ? (PI - ac) : ac;
      float S = ac;
      #pragma unroll
      for (int off = 32; off; off >>= 1) S += __shfl_xor(S, off);
      float A = 2.f * S * (PI/64.f);
      if (A < At) lo = al; else hi = al;
    }
    if (lane == 0) {
      float chv = cosf(hi);
      if (tgt) cthr[row] = chv - 1e-5f;
      else     kthr[row] = 2.f*chv - 1.00002f;
    }
  } else {
    int tid = ((int)blockIdx.x - THRB_)*256 + threadIdx.x;
    if (tid < M_) {
      float th = pix[2*tid], ph = pix[2*tid+1];
      float st = sinf(th);
      float x = st*cosf(ph), y = st*sinf(ph), z = cosf(th);
      r_pix[tid] = make_float4(x, y, z, x*x + y*y + z*z);
      atomicAdd(&cnt[thbkt(th)], 1u);
    }
    int t2 = tid - M_;
    if (t2 >= 0 && t2 < B_*N_) {
      int b = t2 >> 12, n = t2 & (N_-1);
      const float* xb = xxx + b*3*N_;
      float th = xb[n], ph = xb[N_+n], ft = xb[2*N_+n];
      float st = sinf(th);
      r_los[t2] = make_float4(st*cosf(ph), st*sinf(ph), cosf(th), ft);
      atomicAdd(&cnt[256 + b*256 + thbkt(th)], 1u);
    }
    int t3 = tid - M_ - B_*N_;
    if (t3 >= 0 && t3 < B_*H_) gf[t3] = 0.0f;
  }
}

// ---------------- scan ----------------
__global__ __launch_bounds__(256) void scan_vA(
    const unsigned* __restrict__ cnt, int* __restrict__ pstart, int* __restrict__ lstart,
    unsigned* __restrict__ pcur, unsigned* __restrict__ lcur)
{
  __shared__ unsigned buf[256];
  const int t = threadIdx.x;
  for (int arr = 0; arr < 3; ++arr) {
    unsigned v = cnt[arr*256 + t];
    buf[t] = v;
    __syncthreads();
    for (int off = 1; off < 256; off <<= 1) {
      unsigned o = (t >= off) ? buf[t - off] : 0u;
      __syncthreads();
      buf[t] += o;
      __syncthreads();
    }
    unsigned incl = buf[t], excl = incl - v;
    if (arr == 0) {
      pstart[t] = (int)excl; if (t == 255) pstart[256] = (int)incl;
      pcur[t] = excl;
    } else {
      int b = arr - 1;
      lstart[b*257 + t] = (int)excl; if (t == 255) lstart[b*257 + 256] = (int)incl;
      lcur[b*256 + t] = excl;
    }
    __syncthreads();
  }
}

// ---------------- scatter ----------------
__global__ __launch_bounds__(256) void scatter_vA(
    const float* __restrict__ xxx, const float* __restrict__ pix,
    const float4* __restrict__ r_pix, const float4* __restrict__ r_los,
    unsigned* __restrict__ pcur, unsigned* __restrict__ lcur,
    float4* __restrict__ spix, int* __restrict__ sjdx,
    float4* __restrict__ slos, int* __restrict__ sldx)
{
  int tid = blockIdx.x * 256 + threadIdx.x;
  if (tid < M_) {
    int bkt = thbkt(pix[2*tid]);
    unsigned pos = atomicAdd(&pcur[bkt], 1u);
    spix[pos] = r_pix[tid];
    sjdx[pos] = tid;
  } else {
    int t2 = tid - M_;
    if (t2 < B_*N_) {
      int b = t2 >> 12, n = t2 & (N_-1);
      int bkt = thbkt(xxx[b*3*N_ + n]);
      unsigned pos = atomicAdd(&lcur[b*256 + bkt], 1u);
      slos[b*N_ + pos] = r_los[t2];
      sldx[b*N_ + pos] = n;
    }
  }
}

// ---------------- sampler vA: window scan + fused 64-bin histogram select ----------------
__global__ __launch_bounds__(512) void sampler_vA(
    const float* __restrict__ pix,
    const float4* __restrict__ spix, const int* __restrict__ sjdx,
    const float4* __restrict__ slos, const int* __restrict__ sldx,
    const int* __restrict__ lstart, const float4* __restrict__ r_los,
    const float* __restrict__ cthr,
    const float* __restrict__ aw1, const float* __restrict__ ab1,
    const float* __restrict__ aw2, const float* __restrict__ ab2,
    float* __restrict__ pooled)
{
  __shared__ unsigned long long cKey[16][SCAP];   // 36 KB
  __shared__ unsigned long long selKey[16][K_];   // 8 KB
  __shared__ unsigned hist[16][64];               // 4 KB
  __shared__ int bnd[16][16];                     // 1 KB  -> ~50 KB, 3 blocks/CU

  const int tid = threadIdx.x, wv = tid >> 6, lane = tid & 63;
  const int b  = blockIdx.y;
  const int srow0 = blockIdx.x*16 + wv*2, srow1 = srow0 + 1;
  const int r0 = wv*2, r1 = r0 + 1;
  const int m0 = sjdx[srow0], m1 = sjdx[srow1];
  const float4 p0 = spix[srow0], p1 = spix[srow1];
  const float thp0 = pix[2*m0], thp1 = pix[2*m1];
  float th0 = cthr[m0], th1 = cthr[m1];
  const float inv0 = 63.999f / (1.000001f - th0);
  const float inv1 = 63.999f / (1.000001f - th1);
  const float4* sl = slos + b * N_;
  const int* sx = sldx + b * N_;
  const float4* rl = r_los + b * N_;
  const int* ls = lstart + b * 257;
  const unsigned long long ltm = (1ull << lane) - 1ull;

  // wave-local hist zero (no cross-wave use anywhere)
  hist[r0][lane] = 0u; hist[r1][lane] = 0u;

  // phase A: union window scan; candidates + fused histogram
  unsigned cnt0 = 0, cnt1 = 0;
  {
    float al0 = acosf(clamp1(th0)), al1 = acosf(clamp1(th1));
    int blo = thbkt(fminf(thp0 - al0, thp1 - al1) - MG_);
    int bhi = thbkt(fmaxf(thp0 + al0, thp1 + al1) + MG_);
    int jlo = ls[blo], jhi = ls[bhi + 1];
    for (int base = jlo; base < jhi; base += 64) {
      int pos = base + lane;
      bool act = pos < jhi;
      float c0 = -2.f, c1 = -2.f; int n = 0;
      if (act) {
        float4 v = sl[pos]; n = sx[pos];
        c0 = clamp1(v.x*p0.x + v.y*p0.y + v.z*p0.z);
        c1 = clamp1(v.x*p1.x + v.y*p1.y + v.z*p1.z);
      }
      bool pr0 = c0 > th0, pr1 = c1 > th1;
      unsigned long long mk0 = __ballot(pr0);
      if (mk0) {
        unsigned off = (unsigned)__popcll(mk0 & ltm);
        if (pr0) {
          if (cnt0 + off < SCAP) cKey[r0][cnt0 + off] = spack(c0, n);
          atomicAdd(&hist[r0][(int)((c0 - th0) * inv0)], 1u);
        }
        cnt0 += (unsigned)__popcll(mk0);
      }
      unsigned long long mk1 = __ballot(pr1);
      if (mk1) {
        unsigned off = (unsigned)__popcll(mk1 & ltm);
        if (pr1) {
          if (cnt1 + off < SCAP) cKey[r1][cnt1 + off] = spack(c1, n);
          atomicAdd(&hist[r1][(int)((c1 - th1) * inv1)], 1u);
        }
        cnt1 += (unsigned)__popcll(mk1);
      }
    }
  }

  for (int rr = 0; rr < 2; ++rr) {
    const int r = (rr == 0) ? r0 : r1;
    const int m = (rr == 0) ? m0 : m1;
    const float4 p = (rr == 0) ? p0 : p1;
    const float thp = (rr == 0) ? thp0 : thp1;
    float th = (rr == 0) ? th0 : th1;
    float inv = (rr == 0) ? inv0 : inv1;
    unsigned cn = (rr == 0) ? cnt0 : cnt1;

    int tries = 0;
    while (cn < K_ && tries < 3) {
      th = 1.f - 1.6f*(1.f - th); ++tries;
      float al = acosf(clamp1(th));
      int blo = thbkt(thp - al - MG_), bhi = thbkt(thp + al + MG_);
      int jlo = ls[blo], jhi = ls[bhi + 1];
      cn = 0;
      for (int base = jlo; base < jhi; base += 64) {
        int pos = base + lane;
        bool act = pos < jhi;
        float c = -2.f; int n = 0;
        if (act) {
          float4 v = sl[pos]; n = sx[pos];
          c = clamp1(v.x*p.x + v.y*p.y + v.z*p.z);
        }
        bool pr = c > th;
        unsigned long long mk = __ballot(pr);
        if (mk) {
          unsigned off = (unsigned)__popcll(mk & ltm);
          if (pr && cn + off < SCAP) cKey[r][cn + off] = spack(c, n);
          cn += (unsigned)__popcll(mk);
        }
      }
    }

    if (cn < K_ || cn > SCAP) {
      // ultimate exact: 64 rounds bounded argmax over full row
      unsigned long long prev = ~0ull;
      for (int rd = 0; rd < K_; ++rd) {
        unsigned long long best = 0ull;
        for (int i = 0; i < 64; ++i) {
          int n = lane + 64*i;
          float4 v = rl[n];
          float c = clamp1(v.x*p.x + v.y*p.y + v.z*p.z);
          unsigned long long k = spack(c, n);
          if (k < prev && k > best) best = k;
        }
        #pragma unroll
        for (int off = 1; off < 64; off <<= 1) {
          unsigned long long o = shflxor64(best, off);
          best = o > best ? o : best;
        }
        if (lane == 0) selKey[r][rd] = best;
        prev = best;
      }
    } else {
      if (tries > 0) {   // rebuild hist for widened threshold (rare)
        inv = 63.999f / (1.000001f - th);
        hist[r][lane] = 0u;
        for (unsigned base = 0; base < cn; base += 64) {
          unsigned it = base + lane;
          if (it < cn) {
            float c = key2f((unsigned)(cKey[r][it] >> 12));
            atomicAdd(&hist[r][(int)((c - th) * inv)], 1u);
          }
        }
      }
      // suffix-scan over 64 bins (1/lane)
      unsigned g = hist[r][lane], s = g;
      #pragma unroll
      for (int off = 1; off < 64; off <<= 1) {
        unsigned t2 = (unsigned)__shfl_down((int)s, off);
        s += (lane + off < 64) ? t2 : 0u;
      }
      unsigned snext = s - g;                     // cnt_gt(lane)
      unsigned packed = (s >= K_ && snext < K_) ? (((unsigned)(lane+1) << 16) | snext) : 0u;
      #pragma unroll
      for (int off = 32; off; off >>= 1) {
        unsigned o = (unsigned)__shfl_xor((int)packed, off);
        packed = packed > o ? packed : o;
      }
      const int t = (int)(packed >> 16) - 1;
      const unsigned chi = packed & 0xFFFFu;
      const unsigned need = K_ - chi;
      // collect winners (bin > t) + boundary (bin == t)
      unsigned hiC = 0, bdC = 0;
      for (unsigned base = 0; base < cn; base += 64) {
        unsigned it = base + lane;
        bool act = it < cn;
        unsigned long long key = act ? cKey[r][it] : 0ull;
        int bin = -1;
        if (act) bin = (int)((key2f((unsigned)(key >> 12)) - th) * inv);
        bool pHi = act && bin > t;
        bool pBd = act && bin == t;
        unsigned long long mH = __ballot(pHi);
        unsigned offH = (unsigned)__popcll(mH & ltm);
        if (pHi && hiC + offH < K_) selKey[r][hiC + offH] = key;
        hiC += (unsigned)__popcll(mH);
        unsigned long long mB = __ballot(pBd);
        unsigned offB = (unsigned)__popcll(mB & ltm);
        if (pBd && bdC + offB < 16u) bnd[r][bdC + offB] = (int)it;
        bdC += (unsigned)__popcll(mB);
      }
      if (bdC <= 16u) {
        if (lane < (int)bdC) {
          unsigned long long ki = cKey[r][bnd[r][lane]];
          int rank = 0;
          for (int j = 0; j < (int)bdC; ++j) rank += (cKey[r][bnd[r][j]] > ki) ? 1 : 0;
          if ((unsigned)rank < need) selKey[r][chi + rank] = ki;
        }
      } else {
        for (unsigned base = 0; base < cn; base += 64) {
          unsigned it = base + lane;
          if (it < cn) {
            unsigned long long ki = cKey[r][it];
            int bin = (int)((key2f((unsigned)(ki >> 12)) - th) * inv);
            if (bin == t) {
              int rank = 0;
              for (unsigned j = 0; j < cn; ++j) {
                unsigned long long kj = cKey[r][j];
                int bj = (int)((key2f((unsigned)(kj >> 12)) - th) * inv);
                rank += (bj == t && kj > ki) ? 1 : 0;
              }
              if ((unsigned)rank < need) selKey[r][chi + rank] = ki;
            }
          }
        }
      }
    }

    // attention MLP + softmax + weighted pool
    {
      unsigned long long key = selKey[r][lane];
      int n = 4095 - (int)(key & 0xFFFull);
      float c = key2f((unsigned)(key >> 12));
      float xg = rl[n].w;
      float d  = acosf(clamp1(c));
      float acc = ab2[0];
      for (int s2 = 0; s2 < SH_; ++s2)
        acc += fmaxf(xg*aw1[s2] + d*aw1[SH_+s2] + ab1[s2], 0.f) * aw2[s2];
      float mx = acc;
      #pragma unroll
      for (int off = 32; off; off >>= 1) mx = fmaxf(mx, __shfl_xor(mx, off));
      float e = expf(acc - mx);
      float se = e, sxe = e * xg;
      #pragma unroll
      for (int off = 32; off; off >>= 1) { se += __shfl_xor(se, off); sxe += __shfl_xor(sxe, off); }
      if (lane == 0) pooled[b*M_ + m] = sxe / se;
    }
  }
}

// ---------------- knn vA (= v9, proven) ----------------
__global__ __launch_bounds__(512) void knn_vA(
    const float* __restrict__ pix,
    const float4* __restrict__ spix, const int* __restrict__ sjdx,
    const int* __restrict__ pstart, const float4* __restrict__ r_pix,
    const float* __restrict__ kthr, int* __restrict__ nbr)
{
  __shared__ unsigned long long cKey[16][KCAP];

  const int tid = threadIdx.x, wv = tid >> 6, lane = tid & 63;
  const int lr0 = wv*2;
  const int srow0 = blockIdx.x*16 + lr0, srow1 = srow0 + 1;
  const int i0 = sjdx[srow0], i1 = sjdx[srow1];
  const float4 p0 = spix[srow0], p1 = spix[srow1];
  const float thp0 = pix[2*i0], thp1 = pix[2*i1];
  const float t0 = kthr[i0], t1 = kthr[i1];
  const unsigned long long ltm = (1ull << lane) - 1ull;

  unsigned cnt0 = 0, cnt1 = 0;
  {
    float al0 = acosf(clamp1((t0 + 1.00002f)*0.5f));
    float al1 = acosf(clamp1((t1 + 1.00002f)*0.5f));
    int blo = thbkt(fminf(thp0 - al0, thp1 - al1) - MG_);
    int bhi = thbkt(fmaxf(thp0 + al0, thp1 + al1) + MG_);
    int jlo = pstart[blo], jhi = pstart[bhi + 1];
    for (int base = jlo; base < jhi; base += 64) {
      int pos = base + lane;
      bool act = pos < jhi;
      float s0 = -1e30f, s1 = -1e30f; int j = -1;
      if (act) {
        float4 v = spix[pos]; j = sjdx[pos];
        s0 = 2.f*(p0.x*v.x + p0.y*v.y + p0.z*v.z) - v.w;
        s1 = 2.f*(p1.x*v.x + p1.y*v.y + p1.z*v.z) - v.w;
      }
      bool pr0 = act && (j != i0) && (s0 > t0);
      bool pr1 = act && (j != i1) && (s1 > t1);
      unsigned long long mk0 = __ballot(pr0);
      if (mk0) {
        unsigned off = (unsigned)__popcll(mk0 & ltm);
        if (pr0 && cnt0 + off < KCAP) cKey[lr0][cnt0 + off] = kpack(s0, j);
        cnt0 += (unsigned)__popcll(mk0);
      }
      unsigned long long mk1 = __ballot(pr1);
      if (mk1) {
        unsigned off = (unsigned)__popcll(mk1 & ltm);
        if (pr1 && cnt1 + off < KCAP) cKey[lr0+1][cnt1 + off] = kpack(s1, j);
        cnt1 += (unsigned)__popcll(mk1);
      }
    }
  }

  for (int rr = 0; rr < 2; ++rr) {
    const int lr = lr0 + rr;
    const int i  = (rr == 0) ? i0 : i1;
    const float4 pi = (rr == 0) ? p0 : p1;
    const float thp = (rr == 0) ? thp0 : thp1;
    float th = (rr == 0) ? t0 : t1;
    unsigned cn = (rr == 0) ? cnt0 : cnt1;

    int tries = 0;
    while (cn < (unsigned)GK_ && tries < 3) {
      th = 1.6f*th - 0.6f; ++tries;
      float al = acosf(clamp1((th + 1.00002f)*0.5f));
      int blo = thbkt(thp - al - MG_), bhi = thbkt(thp + al + MG_);
      int jlo = pstart[blo], jhi = pstart[bhi + 1];
      cn = 0;
      for (int base = jlo; base < jhi; base += 64) {
        int pos = base + lane;
        bool act = pos < jhi;
        float s = -1e30f; int j = -1;
        if (act) {
          float4 v = spix[pos]; j = sjdx[pos];
          s = 2.f*(pi.x*v.x + pi.y*v.y + pi.z*v.z) - v.w;
        }
        bool pr = act && (j != i) && (s > th);
        unsigned long long mk = __ballot(pr);
        if (mk) {
          unsigned off = (unsigned)__popcll(mk & ltm);
          if (pr && cn + off < KCAP) cKey[lr][cn + off] = kpack(s, j);
          cn += (unsigned)__popcll(mk);
        }
      }
    }

    if (cn >= (unsigned)GK_ && cn <= (unsigned)KCAP) {
      unsigned long long pk[4];
      #pragma unroll
      for (int t2 = 0; t2 < 4; ++t2) {
        int idx = lane + 64*t2;
        pk[t2] = (idx < (int)cn) ? cKey[lr][idx] : 0ull;
      }
      for (int round = 0; round < GK_; ++round) {
        unsigned long long loc = pk[0]; int lt = 0;
        #pragma unroll
        for (int t2 = 1; t2 < 4; ++t2) if (pk[t2] > loc) { loc = pk[t2]; lt = t2; }
        unsigned long long best = loc;
        #pragma unroll
        for (int off = 1; off < 64; off <<= 1) {
          unsigned long long o = shflxor64(best, off);
          best = o > best ? o : best;
        }
        if (loc == best) {
          #pragma unroll
          for (int t2 = 0; t2 < 4; ++t2) if (t2 == lt) pk[t2] = 0ull;
        }
        if (lane == round) nbr[i*GK_ + round] = 16383 - (int)(best & 16383ull);
      }
    } else {
      unsigned long long prev = ~0ull;
      for (int rd = 0; rd < GK_; ++rd) {
        unsigned long long best = 0ull;
        for (int j = lane; j < M_; j += 64) {
          float4 v = r_pix[j];
          float s = 2.f*(pi.x*v.x + pi.y*v.y + pi.z*v.z) - v.w;
          if (j != i) {
            unsigned long long k = kpack(s, j);
            if (k < prev && k > best) best = k;
          }
        }
        #pragma unroll
        for (int off = 1; off < 64; off <<= 1) {
          unsigned long long o = shflxor64(best, off);
          best = o > best ? o : best;
        }
        if (lane == rd) nbr[i*GK_ + rd] = 16383 - (int)(best & 16383ull);
        prev = best;
      }
    }
  }
}

// ---------------- GNN layer 1 fused with proj (readlane matmul) ----------------
__global__ __launch_bounds__(256) void gnn1f_vA(
    const float* __restrict__ pooled, float* __restrict__ hout, const int* __restrict__ nbr,
    const float* __restrict__ pw, const float* __restrict__ pb,
    const float* __restrict__ relw, const float* __restrict__ relb,
    const float* __restrict__ rootw)
{
  __shared__ float wrel[H_*H_], wroot[H_*H_];
  const int tid = threadIdx.x;
  #pragma unroll
  for (int q = 0; q < 16; ++q) {
    int idx = tid + 256*q;
    wrel[idx]  = relw[idx];
    wroot[idx] = rootw[idx];
  }
  __syncthreads();

  const int lane = tid & 63;
  const int wave = tid >> 6;
  const int b = blockIdx.y;
  const int m0 = blockIdx.x * 16 + wave * 4;
  const float* pldb = pooled + (size_t)b * M_;
  const float pwl = pw[lane], pbl = pb[lane], rbl = relb[lane];

  float h[4], agg[4], acc[4];
  #pragma unroll
  for (int t = 0; t < 4; ++t) {
    int m = m0 + t;
    float ps = pldb[m];
    h[t] = fmaxf(ps*pwl + pbl, 0.f);
    float a = 0.f;
    #pragma unroll
    for (int k = 0; k < GK_; ++k) {
      int nb = nbr[m*GK_ + k];
      nb = nb < 0 ? 0 : (nb >= M_ ? M_-1 : nb);
      float pn = pldb[nb];
      a += fmaxf(pn*pwl + pbl, 0.f);
    }
    agg[t] = a;
    acc[t] = rbl;
  }
  #pragma unroll
  for (int c = 0; c < H_; ++c) {
    float wr = wrel[c*H_ + lane], wo = wroot[c*H_ + lane];
    #pragma unroll
    for (int t = 0; t < 4; ++t)
      acc[t] += rdlane(agg[t], c) * wr + rdlane(h[t], c) * wo;
  }
  #pragma unroll
  for (int t = 0; t < 4; ++t)
    hout[((size_t)b*M_ + m0 + t)*H_ + lane] = fmaxf(acc[t], 0.f);
}

// ---------------- GNN layer (generic, readlane matmul) ----------------
__global__ __launch_bounds__(256) void gnn_vA(
    const float* __restrict__ hin, float* __restrict__ hout, const int* __restrict__ nbr,
    const float* __restrict__ relw, const float* __restrict__ relb,
    const float* __restrict__ rootw)
{
  __shared__ float wrel[H_*H_], wroot[H_*H_];
  const int tid = threadIdx.x;
  #pragma unroll
  for (int q = 0; q < 16; ++q) {
    int idx = tid + 256*q;
    wrel[idx]  = relw[idx];
    wroot[idx] = rootw[idx];
  }
  __syncthreads();

  const int lane = tid & 63;
  const int wave = tid >> 6;
  const int b = blockIdx.y;
  const int m0 = blockIdx.x * 16 + wave * 4;
  const float* hb = hin + (size_t)b * M_ * H_;
  const float rbl = relb[lane];

  float h[4], agg[4], acc[4];
  #pragma unroll
  for (int t = 0; t < 4; ++t) {
    int m = m0 + t;
    h[t] = hb[m*H_ + lane];
    float a = 0.f;
    #pragma unroll
    for (int k = 0; k < GK_; ++k) {
      int nb = nbr[m*GK_ + k];
      nb = nb < 0 ? 0 : (nb >= M_ ? M_-1 : nb);
      a += hb[nb*H_ + lane];
    }
    agg[t] = a;
    acc[t] = rbl;
  }
  #pragma unroll
  for (int c = 0; c < H_; ++c) {
    float wr = wrel[c*H_ + lane], wo = wroot[c*H_ + lane];
    #pragma unroll
    for (int t = 0; t < 4; ++t)
      acc[t] += rdlane(agg[t], c) * wr + rdlane(h[t], c) * wo;
  }
  #pragma unroll
  for (int t = 0; t < 4; ++t)
    hout[((size_t)b*M_ + m0 + t)*H_ + lane] = fmaxf(acc[t], 0.f);
}

// ---------------- GNN layer 3 + fused global-mean reduce ----------------
__global__ __launch_bounds__(256) void gnn3r_vA(
    const float* __restrict__ hin, float* __restrict__ gf, const int* __restrict__ nbr,
    const float* __restrict__ relw, const float* __restrict__ relb,
    const float* __restrict__ rootw)
{
  __shared__ float wrel[H_*H_], wroot[H_*H_];
  __shared__ float gacc[H_];
  const int tid = threadIdx.x;
  #pragma unroll
  for (int q = 0; q < 16; ++q) {
    int idx = tid + 256*q;
    wrel[idx]  = relw[idx];
    wroot[idx] = rootw[idx];
  }
  if (tid < H_) gacc[tid] = 0.f;
  __syncthreads();

  const int lane = tid & 63;
  const int wave = tid >> 6;
  const int b = blockIdx.y;
  const int m0 = blockIdx.x * 16 + wave * 4;
  const float* hb = hin + (size_t)b * M_ * H_;
  const float rbl = relb[lane];

  float h[4], agg[4], acc[4];
  #pragma unroll
  for (int t = 0; t < 4; ++t) {
    int m = m0 + t;
    h[t] = hb[m*H_ + lane];
    float a = 0.f;
    #pragma unroll
    for (int k = 0; k < GK_; ++k) {
      int nb = nbr[m*GK_ + k];
      nb = nb < 0 ? 0 : (nb >= M_ ? M_-1 : nb);
      a += hb[nb*H_ + lane];
    }
    agg[t] = a;
    acc[t] = rbl;
  }
  #pragma unroll
  for (int c = 0; c < H_; ++c) {
    float wr = wrel[c*H_ + lane], wo = wroot[c*H_ + lane];
    #pragma unroll
    for (int t = 0; t < 4; ++t)
      acc[t] += rdlane(agg[t], c) * wr + rdlane(h[t], c) * wo;
  }
  float ps = fmaxf(acc[0], 0.f) + fmaxf(acc[1], 0.f) + fmaxf(acc[2], 0.f) + fmaxf(acc[3], 0.f);
  atomicAdd(&gacc[lane], ps);
  __syncthreads();
  if (tid < H_) atomicAdd(&gf[b*H_ + tid], gacc[tid]);
}

// ---------------- head ----------------
__global__ __launch_bounds__(256) void head_vA(
    const float* __restrict__ gf, const float* __restrict__ w1,
    const float* __restrict__ b1, const float* __restrict__ w2,
    const float* __restrict__ b2, float* __restrict__ out)
{
  __shared__ float gfm[B_][H_], hid[B_][H_];
  const int tid = threadIdx.x;
  if (tid < B_*H_) gfm[tid >> 6][tid & 63] = gf[tid] * (1.f / (float)M_);
  __syncthreads();
  if (tid < B_*H_) {
    int b = tid >> 6, j = tid & 63;
    float acc = b1[j];
    for (int c = 0; c < H_; ++c) acc += gfm[b][c] * w1[c*H_ + j];
    hid[b][j] = fmaxf(acc, 0.f);
  }
  __syncthreads();
  for (int t = tid; t < B_*NC_; t += 256) {
    int b = t / NC_, o = t - b*NC_;
    float acc = b2[o];
    for (int j = 0; j < H_; ++j) acc += hid[b][j] * w2[j*NC_ + o];
    out[t] = acc;
  }
}

extern "C" void kernel_launch(void* const* d_in, const int* in_sizes, int n_in,
                              void* d_out, int out_size, void* d_ws, size_t ws_size,
                              hipStream_t stream)
{
  float* out = (float*)d_out;

  const size_t need = (size_t)M_*16 + (size_t)B_*N_*16 + (size_t)B_*M_*4
                    + (size_t)M_*GK_*4 + 2*(size_t)B_*M_*H_*4 + (size_t)B_*H_*4;
  bool ok_ws = ws_size >= need;
  bool ok_in = (n_in == 15) && (out_size == B_*NC_)
            && in_sizes[0] == B_*3*N_ && in_sizes[1] == M_*2
            && in_sizes[2] == 2*SH_ && in_sizes[5] == 1
            && in_sizes[8] == 3*H_*H_ && in_sizes[13] == H_*NC_;
  if (!ok_ws || !ok_in) {
    sentinel_vA<<<(out_size + 255)/256, 256, 0, stream>>>(out, out_size, ok_in ? 42.f : 43.f);
    return;
  }

  const float* xxx    = (const float*)d_in[0];
  const float* pix    = (const float*)d_in[1];
  const float* att_w1 = (const float*)d_in[2];
  const float* att_b1 = (const float*)d_in[3];
  const float* att_w2 = (const float*)d_in[4];
  const float* att_b2 = (const float*)d_in[5];
  const float* proj_w = (const float*)d_in[6];
  const float* proj_b = (const float*)d_in[7];
  const float* rel_w  = (const float*)d_in[8];
  const float* rel_b  = (const float*)d_in[9];
  const float* root_w = (const float*)d_in[10];
  const float* out_w1 = (const float*)d_in[11];
  const float* out_b1 = (const float*)d_in[12];
  const float* out_w2 = (const float*)d_in[13];
  const float* out_b2 = (const float*)d_in[14];

  char* w = (char*)d_ws;
  float4* r_pix = (float4*)w;  w += (size_t)M_ * 16;
  float4* r_los = (float4*)w;  w += (size_t)B_ * N_ * 16;
  float*  pooled = (float*)w;  w += (size_t)B_ * M_ * 4;
  int*    nbr = (int*)w;       w += (size_t)M_ * GK_ * 4;
  float*  h0 = (float*)w;      w += (size_t)B_ * M_ * H_ * 4;
  float*  h1 = (float*)w;      w += (size_t)B_ * M_ * H_ * 4;
  float*  gf = (float*)w;      w += (size_t)B_ * H_ * 4;

  // sort/threshold scratch aliases h0 (dead until gnn layer 2 writes it)
  float*  kthr = h0;                                   // M
  float*  cthr = h0 + M_;                              // M
  float4* spix = (float4*)(h0 + 2*M_);                 // M float4
  int*    sjdx = (int*)(h0 + 6*M_);                    // M
  float4* slos = (float4*)(h0 + 7*M_);                 // B*N float4
  int*    sldx = (int*)(h0 + 7*M_ + 4*B_*N_);          // B*N
  unsigned* cnt = (unsigned*)(h0 + 7*M_ + 5*B_*N_);    // 768
  int*    pstart = (int*)(cnt + 768);                  // 257
  int*    lstart = pstart + 257;                       // 2*257
  unsigned* pcur = (unsigned*)(lstart + 514);          // 256
  unsigned* lcur = pcur + 256;                         // 512

  hipMemsetAsync(cnt, 0, 768*sizeof(unsigned), stream);
  prepthr_vA<<<THRB_ + PREPB_, 256, 0, stream>>>(xxx, pix, r_pix, r_los, gf, kthr, cthr, cnt);
  scan_vA<<<1, 256, 0, stream>>>(cnt, pstart, lstart, pcur, lcur);
  scatter_vA<<<(M_ + B_*N_ + 255)/256, 256, 0, stream>>>(xxx, pix, r_pix, r_los, pcur, lcur,
                                                         spix, sjdx, slos, sldx);
  sampler_vA<<<dim3(M_/16, B_), 512, 0, stream>>>(pix, spix, sjdx, slos, sldx, lstart, r_los,
                                                  cthr, att_w1, att_b1, att_w2, att_b2, pooled);
  knn_vA<<<M_/16, 512, 0, stream>>>(pix, spix, sjdx, pstart, r_pix, kthr, nbr);
  gnn1f_vA<<<dim3(M_/16, B_), 256, 0, stream>>>(pooled, h1, nbr, proj_w, proj_b,
                                                rel_w + 0*H_*H_, rel_b + 0*H_, root_w + 0*H_*H_);
  gnn_vA<<<dim3(M_/16, B_), 256, 0, stream>>>(h1, h0, nbr, rel_w + 1*H_*H_, rel_b + 1*H_, root_w + 1*H_*H_);
  gnn3r_vA<<<dim3(M_/16, B_), 256, 0, stream>>>(h0, gf, nbr, rel_w + 2*H_*H_, rel_b + 2*H_, root_w + 2*H_*H_);
  head_vA<<<1, 256, 0, stream>>>(gf, out_w1, out_b1, out_w2, out_b2, out);
}